// Round 11
// baseline (398.939 us; speedup 1.0000x reference)
//
#include <hip/hip_runtime.h>

typedef unsigned short u16;
typedef unsigned int u32;
typedef __attribute__((ext_vector_type(4))) float f32x4;
typedef __attribute__((ext_vector_type(16))) float f32x16;
typedef __attribute__((ext_vector_type(8))) __bf16 bf16x8;
typedef __attribute__((ext_vector_type(8))) unsigned short u16x8;
typedef __attribute__((ext_vector_type(4))) unsigned short u16x4;

__device__ __forceinline__ u16 f2bf(float f) {
  __bf16 h = (__bf16)f;
  union { __bf16 h; u16 u; } v; v.h = h;
  return v.u;
}

__device__ __forceinline__ float bf2f(u16 u) {
  union { unsigned u; float f; } v; v.u = ((unsigned)u) << 16;
  return v.f;
}

__device__ __forceinline__ u32 pk2(float a, float b) {
  return (u32)f2bf(a) | ((u32)f2bf(b) << 16);
}

__device__ __forceinline__ void async16(const void* g, void* l) {
  __builtin_amdgcn_global_load_lds(
      (const __attribute__((address_space(1))) unsigned int*)g,
      (__attribute__((address_space(3))) unsigned int*)l, 16, 0, 0);
}

__device__ __forceinline__ void barrier_f() {
  asm volatile("" ::: "memory");
  __builtin_amdgcn_s_barrier();
  asm volatile("" ::: "memory");
}

// ---------------- elementwise f32 -> bf16 ----------------
__global__ __launch_bounds__(256) void cvt_f32_bf16(const float* __restrict__ in,
                                                    u16* __restrict__ out, int n4) {
  int i = blockIdx.x * 256 + threadIdx.x;
  if (i >= n4) return;
  f32x4 v = *(const f32x4*)(in + (long)i * 4);
  u16x4 o;
#pragma unroll
  for (int j = 0; j < 4; j++) o[j] = f2bf(v[j]);
  *(u16x4*)(out + (long)i * 4) = o;
}

// ---------------- transpose + convert: W[K][N] f32 -> Wt[N][K] bf16 ----------------
__global__ __launch_bounds__(256) void transpose_cvt(const float* __restrict__ W,
                                                     u16* __restrict__ Wt, int K, int N) {
  __shared__ float tile[32][33];
  int n0 = blockIdx.x * 32, k0 = blockIdx.y * 32;
  int tx = threadIdx.x & 31, ty = threadIdx.x >> 5;
#pragma unroll
  for (int i = 0; i < 32; i += 8)
    tile[ty + i][tx] = W[(long)(k0 + ty + i) * N + n0 + tx];
  __syncthreads();
#pragma unroll
  for (int i = 0; i < 32; i += 8)
    Wt[(long)(n0 + ty + i) * K + k0 + tx] = f2bf(tile[tx][ty + i]);
}

// ======== 8-phase GEMM 256x256, BK=64, 8 waves (2M x 4N), counted vmcnt ========
// QKV: col<1024 -> qb prescaled; [1024,2048) -> kt2 chunked; >=2048 -> vt2 chunked.
// SPLITK: raw bf16 partials to Cp + z*M*N (reduce fused into LN).
template <int BIAS, int GELU, int OBF, int QKV, int SPLITK>
__global__ __launch_bounds__(512, 1) void gemm8p(const u16* __restrict__ A,
                                                 const u16* __restrict__ Bt,
                                                 void* __restrict__ Cp,
                                                 const float* __restrict__ bias,
                                                 u16* __restrict__ kt2,
                                                 u16* __restrict__ vt2,
                                                 int M, int N, int Kst, int Klen) {
  __shared__ u16 As[2][256 * 64];
  __shared__ u16 Bs[2][256 * 64];
  const int t = threadIdx.x, wid = t >> 6, ln = t & 63;
  const int lr = ln & 15, lg = ln >> 4;
  const int wr = wid >> 2, wc = wid & 3;

  const int gx = gridDim.x, gy = gridDim.y;
  const int nwg = gx * gy * gridDim.z;
  const int flat = (blockIdx.z * gy + blockIdx.y) * gx + blockIdx.x;
  const int cpx = nwg >> 3;
  const int swz = (flat & 7) * cpx + (flat >> 3);
  const int sx = swz % gx, rest = swz / gx;
  const int sy = rest % gy, sz = rest / gy;
  const int m0 = sy * 256, n0 = sx * 256;
  const long zo = (long)sz * Klen;
  const int NT = Klen >> 6;

  const int srow = t >> 3;
  const int sch = ((t & 7) ^ (srow & 7)) * 8;
  const u16* gA = A + (long)(m0 + srow) * Kst + zo + sch;
  const u16* gB = Bt + (long)(n0 + srow) * Kst + zo + sch;
  const long KL = Kst;

#define STAGE_A(tt, h)                                                     \
  {                                                                        \
    const u16* s_ = gA + (long)((h) * 128) * KL + (long)(tt) * 64;         \
    char* d_ = (char*)As + ((tt) & 1) * 32768 + (h) * 16384 + wid * 1024;  \
    async16(s_, d_);                                                       \
    async16(s_ + 64 * KL, d_ + 8192);                                      \
  }
#define STAGE_B(tt, h)                                                     \
  {                                                                        \
    const u16* s_ = gB + (long)((h) * 128) * KL + (long)(tt) * 64;         \
    char* d_ = (char*)Bs + ((tt) & 1) * 32768 + (h) * 16384 + wid * 1024;  \
    async16(s_, d_);                                                       \
    async16(s_ + 64 * KL, d_ + 8192);                                      \
  }

  f32x4 acc[8][4] = {};
  const int cx0 = (lg ^ (lr & 7)) * 16;
  const int cx1 = ((4 + lg) ^ (lr & 7)) * 16;

  STAGE_A(0, 0); STAGE_A(0, 1);
  STAGE_B(0, 0); STAGE_B(0, 1);
  STAGE_A(1, 0); STAGE_A(1, 1);

  for (int tK = 0; tK < NT; ++tK) {
    const int cur = tK & 1;
    const char* ldsA = (const char*)As + cur * 32768;
    const char* ldsB = (const char*)Bs + cur * 32768;
    if (tK == NT - 1) {
      asm volatile("s_waitcnt vmcnt(0)" ::: "memory");
    } else {
      asm volatile("s_waitcnt vmcnt(4)" ::: "memory");
    }
    barrier_f();

    bf16x8 aLo[4][2], aHi[4][2], bLo[2][2], bHi[2][2];
#pragma unroll
    for (int mf = 0; mf < 4; mf++) {
      int row = wr * 128 + mf * 16 + lr;
      aLo[mf][0] = *(const bf16x8*)(ldsA + row * 128 + cx0);
      aLo[mf][1] = *(const bf16x8*)(ldsA + row * 128 + cx1);
    }
#pragma unroll
    for (int nf = 0; nf < 2; nf++) {
      int row = wc * 64 + nf * 16 + lr;
      bLo[nf][0] = *(const bf16x8*)(ldsB + row * 128 + cx0);
      bLo[nf][1] = *(const bf16x8*)(ldsB + row * 128 + cx1);
    }
    if (tK + 1 < NT) STAGE_B(tK + 1, 0);
    barrier_f();
    __builtin_amdgcn_s_setprio(1);
#pragma unroll
    for (int mf = 0; mf < 4; mf++)
#pragma unroll
      for (int nf = 0; nf < 2; nf++) {
        acc[mf][nf] = __builtin_amdgcn_mfma_f32_16x16x32_bf16(aLo[mf][0], bLo[nf][0], acc[mf][nf], 0, 0, 0);
        acc[mf][nf] = __builtin_amdgcn_mfma_f32_16x16x32_bf16(aLo[mf][1], bLo[nf][1], acc[mf][nf], 0, 0, 0);
      }
    __builtin_amdgcn_s_setprio(0);
    barrier_f();

#pragma unroll
    for (int mf = 0; mf < 4; mf++) {
      int row = wr * 128 + (mf + 4) * 16 + lr;
      aHi[mf][0] = *(const bf16x8*)(ldsA + row * 128 + cx0);
      aHi[mf][1] = *(const bf16x8*)(ldsA + row * 128 + cx1);
    }
    if (tK + 1 < NT) STAGE_B(tK + 1, 1);
    barrier_f();
    __builtin_amdgcn_s_setprio(1);
#pragma unroll
    for (int mf = 0; mf < 4; mf++)
#pragma unroll
      for (int nf = 0; nf < 2; nf++) {
        acc[mf + 4][nf] = __builtin_amdgcn_mfma_f32_16x16x32_bf16(aHi[mf][0], bLo[nf][0], acc[mf + 4][nf], 0, 0, 0);
        acc[mf + 4][nf] = __builtin_amdgcn_mfma_f32_16x16x32_bf16(aHi[mf][1], bLo[nf][1], acc[mf + 4][nf], 0, 0, 0);
      }
    __builtin_amdgcn_s_setprio(0);
    barrier_f();

#pragma unroll
    for (int nf = 0; nf < 2; nf++) {
      int row = wc * 64 + (nf + 2) * 16 + lr;
      bHi[nf][0] = *(const bf16x8*)(ldsB + row * 128 + cx0);
      bHi[nf][1] = *(const bf16x8*)(ldsB + row * 128 + cx1);
    }
    if (tK + 2 < NT) STAGE_A(tK + 2, 0);
    barrier_f();
    __builtin_amdgcn_s_setprio(1);
#pragma unroll
    for (int mf = 0; mf < 4; mf++)
#pragma unroll
      for (int nf = 0; nf < 2; nf++) {
        acc[mf][nf + 2] = __builtin_amdgcn_mfma_f32_16x16x32_bf16(aLo[mf][0], bHi[nf][0], acc[mf][nf + 2], 0, 0, 0);
        acc[mf][nf + 2] = __builtin_amdgcn_mfma_f32_16x16x32_bf16(aLo[mf][1], bHi[nf][1], acc[mf][nf + 2], 0, 0, 0);
      }
    __builtin_amdgcn_s_setprio(0);
    barrier_f();

    if (tK + 2 < NT) STAGE_A(tK + 2, 1);
    barrier_f();
    __builtin_amdgcn_s_setprio(1);
#pragma unroll
    for (int mf = 0; mf < 4; mf++)
#pragma unroll
      for (int nf = 0; nf < 2; nf++) {
        acc[mf + 4][nf + 2] = __builtin_amdgcn_mfma_f32_16x16x32_bf16(aHi[mf][0], bHi[nf][0], acc[mf + 4][nf + 2], 0, 0, 0);
        acc[mf + 4][nf + 2] = __builtin_amdgcn_mfma_f32_16x16x32_bf16(aHi[mf][1], bHi[nf][1], acc[mf + 4][nf + 2], 0, 0, 0);
      }
    __builtin_amdgcn_s_setprio(0);
    barrier_f();
  }
#undef STAGE_A
#undef STAGE_B

  u16* const Cu = (u16*)Cp + (SPLITK ? (long)sz * M * N : 0);
#pragma unroll
  for (int mf = 0; mf < 8; mf++) {
    int rbase = m0 + wr * 128 + mf * 16 + lg * 4;
#pragma unroll
    for (int nf = 0; nf < 4; nf++) {
      int col = n0 + wc * 64 + nf * 16 + lr;
      float bv = BIAS ? bias[col] : 0.f;
      if (QKV) {
        int bq = rbase >> 11;
        if (col < 1024) {
#pragma unroll
          for (int r = 0; r < 4; r++)
            ((u16*)Cp)[(long)(rbase + r) * 1024 + col] = f2bf(acc[mf][nf][r] * 0.18033688011112043f);
        } else if (col < 2048) {
          int hd = col - 1024, h_ = hd >> 6, d = hd & 63;
#pragma unroll
          for (int r = 0; r < 4; r++) {
            int key = (rbase + r) & 2047;
            kt2[((((long)(bq * 16 + h_) * 32 + (key >> 6)) * 8 + (d >> 3)) * 64 + (key & 63)) * 8 + (d & 7)] =
                f2bf(acc[mf][nf][r]);
          }
        } else {
          int hd = col - 2048, h_ = hd >> 6, d = hd & 63;
          int key0 = rbase & 2047;
          u16x4 o4;
#pragma unroll
          for (int r = 0; r < 4; r++) o4[r] = f2bf(acc[mf][nf][r]);
          *(u16x4*)&vt2[((((long)(bq * 16 + h_) * 32 + (key0 >> 6)) * 8 + ((key0 >> 3) & 7)) * 64 + d) * 8 + (key0 & 7)] = o4;
        }
      } else if (SPLITK) {
#pragma unroll
        for (int r = 0; r < 4; r++)
          Cu[(long)(rbase + r) * N + col] = f2bf(acc[mf][nf][r]);
      } else {
#pragma unroll
        for (int r = 0; r < 4; r++) {
          float v = acc[mf][nf][r] + bv;
          if (GELU) v = v / (1.f + __expf(-1.702f * v));
          if (OBF) ((u16*)Cp)[(long)(rbase + r) * N + col] = f2bf(v);
          else ((float*)Cp)[(long)(rbase + r) * N + col] = v;
        }
      }
    }
  }
}

// ---------------- flash attention v4: 32x32 MFMA, KVBLK=128, ones-MFMA row-sum ----------------
// qb: [8192][1024] prescaled Q. kt2/vt2: chunk-major tiles (64-key tile = 4KB contiguous).
__global__ __launch_bounds__(512, 4) void attn_kernel(const u16* __restrict__ qb,
                                                      const u16* __restrict__ kt2,
                                                      const u16* __restrict__ vt2,
                                                      u16* __restrict__ out) {
  const int bh = blockIdx.y, h = bh & 15;
  const int q0 = blockIdx.x * 256;
  const int t = threadIdx.x, wv = t >> 6, ln = t & 63;
  const int lq = ln & 31, hi = ln >> 5;
  __shared__ u16 Ks[2][8192];   // 2 x 16KB: tile-pair (128 keys), [sub][dchunk8][key64][8]
  __shared__ u16 Vs[2][8192];   // 2 x 16KB: [sub][keychunk8][d64][8]   (64KB total)
  const long tok0 = (long)(bh >> 4) * 2048;

  // Q B-frags: col=q=lq, k(d) = c*16 + hi*8 + j
  bf16x8 bQ[4];
  {
    long row = tok0 + q0 + wv * 32 + lq;
    const u16* qp = &qb[row * 1024 + h * 64 + hi * 8];
#pragma unroll
    for (int c = 0; c < 4; c++) bQ[c] = *(const bf16x8*)(qp + c * 16);
  }

  // staging: threads 0-255 stage K, 256-511 stage V; 4 async16/thread per tile-pair
  const int isK = (t < 256);
  const int tt = t & 255;
  const u16* gS = (isK ? kt2 : vt2) + (long)bh * 131072 + tt * 8;
  char* const dS = (isK ? (char*)&Ks[0][0] : (char*)&Vs[0][0]) + (wv & 3) * 1024;

  f32x16 accO0 = {}, accO1 = {}, accL = {};

  bf16x8 aOnes;
  {
    union { u16x8 u; bf16x8 b; } ou;
#pragma unroll
    for (int j = 0; j < 8; j++) ou.u[j] = 0x3F80;
    aOnes = ou.b;
  }

  // prologue: tile-pair 0 into buffer 0
#pragma unroll
  for (int i = 0; i < 4; i++) async16(gS + i * 2048, dS + i * 4096);
  gS += 8192;

  for (int it = 0; it < 16; ++it) {
    const int cur = it & 1;
    if (it < 15) {
      char* nS = dS + (cur ^ 1) * 16384;
#pragma unroll
      for (int i = 0; i < 4; i++) async16(gS + i * 2048, nS + i * 4096);
      gS += 8192;
      asm volatile("s_waitcnt vmcnt(4)" ::: "memory");
    } else {
      asm volatile("s_waitcnt vmcnt(0)" ::: "memory");
    }
    __builtin_amdgcn_s_barrier();
    __builtin_amdgcn_sched_barrier(0);

#pragma unroll
    for (int sub = 0; sub < 2; ++sub) {
      const u16* Kc = &Ks[cur][sub * 4096];
      const u16* Vc = &Vs[cur][sub * 4096];

      // ---- S^T = K Q^T (2 key-blocks of 32), exp2, pack P into B-frags ----
      u32 frag[4][4];
#pragma unroll
      for (int kb = 0; kb < 2; kb++) {
        f32x16 s = {};
        __builtin_amdgcn_s_setprio(1);
#pragma unroll
        for (int c = 0; c < 4; c++) {
          bf16x8 aK = *(const bf16x8*)&Kc[((c * 2 + hi) * 64 + kb * 32 + lq) * 8];
          s = __builtin_amdgcn_mfma_f32_32x32x16_bf16(aK, bQ[c], s, 0, 0, 0);
        }
        __builtin_amdgcn_s_setprio(0);
        float pv[16];
#pragma unroll
        for (int r = 0; r < 16; r++) pv[r] = exp2f(s[r]);
#pragma unroll
        for (int cc = 0; cc < 2; cc++) {
          u32 dA0 = pk2(pv[8 * cc + 0], pv[8 * cc + 1]);
          u32 dA1 = pk2(pv[8 * cc + 2], pv[8 * cc + 3]);
          u32 dB0 = pk2(pv[8 * cc + 4], pv[8 * cc + 5]);
          u32 dB1 = pk2(pv[8 * cc + 6], pv[8 * cc + 7]);
          u32 e0 = (u32)__shfl_xor((int)dA0, 32);
          u32 e1 = (u32)__shfl_xor((int)dA1, 32);
          u32 f0 = (u32)__shfl_xor((int)dB0, 32);
          u32 f1 = (u32)__shfl_xor((int)dB1, 32);
          frag[kb * 2 + cc][0] = hi ? f0 : dA0;
          frag[kb * 2 + cc][1] = hi ? f1 : dA1;
          frag[kb * 2 + cc][2] = hi ? dB0 : e0;
          frag[kb * 2 + cc][3] = hi ? dB1 : e1;
        }
      }

      // ---- O^T += V^T P^T ; L += 1^T P^T (ones-MFMA row-sum, no serial chain) ----
      __builtin_amdgcn_s_setprio(1);
#pragma unroll
      for (int c2 = 0; c2 < 4; c2++) {
        union { u32 u[4]; bf16x8 v; } pb;
        pb.u[0] = frag[c2][0]; pb.u[1] = frag[c2][1];
        pb.u[2] = frag[c2][2]; pb.u[3] = frag[c2][3];
        bf16x8 aV0 = *(const bf16x8*)&Vc[((c2 * 2 + hi) * 64 + lq) * 8];
        bf16x8 aV1 = *(const bf16x8*)&Vc[((c2 * 2 + hi) * 64 + 32 + lq) * 8];
        accL = __builtin_amdgcn_mfma_f32_32x32x16_bf16(aOnes, pb.v, accL, 0, 0, 0);
        accO0 = __builtin_amdgcn_mfma_f32_32x32x16_bf16(aV0, pb.v, accO0, 0, 0, 0);
        accO1 = __builtin_amdgcn_mfma_f32_32x32x16_bf16(aV1, pb.v, accO1, 0, 0, 0);
      }
      __builtin_amdgcn_s_setprio(0);
    }
    __builtin_amdgcn_s_barrier();
    __builtin_amdgcn_sched_barrier(0);
  }

  // accL: every reg = sum over all 2048 keys for col q=lq -> no cross-lane reduce
  float inv = 1.f / accL[0];
  long tq = tok0 + q0 + wv * 32 + lq;
  u16* op = &out[tq * 1024 + h * 64 + hi * 4];
#pragma unroll
  for (int qd = 0; qd < 4; qd++) {
    u16x4 o4, o5;
#pragma unroll
    for (int j = 0; j < 4; j++) {
      o4[j] = f2bf(accO0[qd * 4 + j] * inv);
      o5[j] = f2bf(accO1[qd * 4 + j] * inv);
    }
    *(u16x4*)(op + qd * 8) = o4;
    *(u16x4*)(op + 32 + qd * 8) = o5;
  }
}

// ---------------- fused add + layernorm: v = x + p0 + p1 + bias ----------------
// XBF: x input is bf16. OF32: write f32 out; else write bf16 out.
template <int XBF, int OF32>
__global__ __launch_bounds__(256) void ln_kernel(const void* __restrict__ xin,
                                                 const u16* __restrict__ p0,
                                                 const u16* __restrict__ p1,
                                                 const float* __restrict__ bias,
                                                 const float* __restrict__ g,
                                                 const float* __restrict__ be,
                                                 float* __restrict__ of,
                                                 u16* __restrict__ ob) {
  int row = blockIdx.x, t = threadIdx.x;
  long base = (long)row * 1024 + t * 4;
  f32x4 a;
  if (XBF) {
    u16x4 xa = *((const u16x4*)xin + row * 256 + t);
#pragma unroll
    for (int j = 0; j < 4; j++) a[j] = bf2f(xa[j]);
  } else {
    a = *((const f32x4*)xin + row * 256 + t);
  }
  u16x4 u0 = *(const u16x4*)(p0 + base);
  u16x4 u1 = *(const u16x4*)(p1 + base);
  f32x4 bb4 = *(const f32x4*)(bias + t * 4);
  f32x4 v;
#pragma unroll
  for (int j = 0; j < 4; j++) v[j] = a[j] + bf2f(u0[j]) + bf2f(u1[j]) + bb4[j];
  float s = v[0] + v[1] + v[2] + v[3];
  float ss = v[0] * v[0] + v[1] * v[1] + v[2] * v[2] + v[3] * v[3];
#pragma unroll
  for (int o = 1; o < 64; o <<= 1) { s += __shfl_xor(s, o); ss += __shfl_xor(ss, o); }
  __shared__ float sm[8];
  if ((t & 63) == 0) { sm[t >> 6] = s; sm[4 + (t >> 6)] = ss; }
  __syncthreads();
  s = sm[0] + sm[1] + sm[2] + sm[3];
  ss = sm[4] + sm[5] + sm[6] + sm[7];
  float mu = s * 0.0009765625f;
  float var = ss * 0.0009765625f - mu * mu;
  float inv = rsqrtf(var + 1e-5f);
  f32x4 gg = *(const f32x4*)(g + t * 4);
  f32x4 bb = *(const f32x4*)(be + t * 4);
  f32x4 y;
#pragma unroll
  for (int j = 0; j < 4; j++) y[j] = (v[j] - mu) * inv * gg[j] + bb[j];
  if (OF32) {
    *(f32x4*)(of + base) = y;
  } else {
    u16x4 o4;
#pragma unroll
    for (int j = 0; j < 4; j++) o4[j] = f2bf(y[j]);
    *(u16x4*)(ob + base) = o4;
  }
}

// ---------------- launch ----------------
extern "C" void kernel_launch(void* const* d_in, const int* in_sizes, int n_in,
                              void* d_out, int out_size, void* d_ws, size_t ws_size,
                              hipStream_t stream) {
  const float* x = (const float*)d_in[0];
  const float* Wqkv = (const float*)d_in[1];
  const float* Wo = (const float*)d_in[2];
  const float* bo = (const float*)d_in[3];
  const float* g1 = (const float*)d_in[4];
  const float* be1 = (const float*)d_in[5];
  const float* W1 = (const float*)d_in[6];
  const float* b1 = (const float*)d_in[7];
  const float* W2 = (const float*)d_in[8];
  const float* b2 = (const float*)d_in[9];
  const float* g2 = (const float*)d_in[10];
  const float* be2 = (const float*)d_in[11];
  float* out = (float*)d_out;
  char* ws = (char*)d_ws;

  // workspace layout (bytes), lifetime-overlaid (~159.4MB):
  u16* xb = (u16*)(ws + 0);                 // 16.78M [cvt -> qkv]
  u16* qb = (u16*)(ws + 16777216);          // 16.78M [qkv -> attn]
  u16* kt2b = (u16*)(ws + 33554432);        // 16.78M [qkv -> attn]
  u16* vt2b = (u16*)(ws + 50331648);        // 16.78M [qkv -> attn]
  u16* h1b = (u16*)(ws + 0);                // 67.11M [mlp1 -> mlp2] reuses xb+qb+kt2+vt2
  u16* attnb = (u16*)(ws + 67108864);       // 16.78M [attn -> proj]
  u16* x1b = (u16*)(ws + 83886080);         // 16.78M [ln1 -> ln2]
  u16* pp = (u16*)(ws + 100663296);         // 33.55M [proj partials -> ln1]
  u16* ffp = (u16*)(ws + 100663296);        // 33.55M [mlp2 partials -> ln2] reuses pp
  u16* wqkvt = (u16*)(ws + 134217728);      // 6.29M
  u16* wot = (u16*)(ws + 140509184);        // 2.10M
  u16* w1t = (u16*)(ws + 142606336);        // 8.39M
  u16* w2t = (u16*)(ws + 150994944);        // 8.39M (end 159.4M)

  cvt_f32_bf16<<<8192, 256, 0, stream>>>(x, xb, 2097152);
  transpose_cvt<<<dim3(96, 32), 256, 0, stream>>>(Wqkv, wqkvt, 1024, 3072);
  transpose_cvt<<<dim3(32, 32), 256, 0, stream>>>(Wo, wot, 1024, 1024);
  transpose_cvt<<<dim3(128, 32), 256, 0, stream>>>(W1, w1t, 1024, 4096);
  transpose_cvt<<<dim3(32, 128), 256, 0, stream>>>(W2, w2t, 4096, 1024);
  // qkv = x @ Wqkv: Q prescaled -> qb; K -> kt2 chunked; V -> vt2 chunked
  gemm8p<0, 0, 0, 1, 0><<<dim3(12, 32, 1), 512, 0, stream>>>(
      xb, wqkvt, qb, nullptr, kt2b, vt2b, 8192, 3072, 1024, 1024);
  attn_kernel<<<dim3(8, 64), 512, 0, stream>>>(qb, kt2b, vt2b, attnb);
  // proj partials = attn @ Wo (split-K x2, bf16 partials; bias+reduce in LN1)
  gemm8p<0, 0, 0, 0, 1><<<dim3(4, 32, 2), 512, 0, stream>>>(
      attnb, wot, pp, nullptr, nullptr, nullptr, 8192, 1024, 1024, 512);
  // x1 = LN(x + pp0 + pp1 + bo) -> bf16 only
  ln_kernel<0, 0><<<8192, 256, 0, stream>>>(x, pp, pp + (long)8192 * 1024, bo,
                                            g1, be1, nullptr, x1b);
  // h1 = gelu(x1 @ W1 + b1)
  gemm8p<1, 1, 1, 0, 0><<<dim3(16, 32, 1), 512, 0, stream>>>(
      x1b, w1t, h1b, b1, nullptr, nullptr, 8192, 4096, 1024, 1024);
  // ff partials = h1 @ W2 (split-K x2, bf16 partials; bias+reduce in LN2)
  gemm8p<0, 0, 0, 0, 1><<<dim3(4, 32, 2), 512, 0, stream>>>(
      h1b, w2t, ffp, nullptr, nullptr, nullptr, 8192, 1024, 4096, 2048);
  // out = LN(x1 + ffp0 + ffp1 + b2) -> f32
  ln_kernel<1, 1><<<8192, 256, 0, stream>>>(x1b, ffp, ffp + (long)8192 * 1024, b2,
                                            g2, be2, out, nullptr);
}

// Round 12
// 387.499 us; speedup vs baseline: 1.0295x; 1.0295x over previous
//
#include <hip/hip_runtime.h>

typedef unsigned short u16;
typedef unsigned int u32;
typedef __attribute__((ext_vector_type(4))) float f32x4;
typedef __attribute__((ext_vector_type(16))) float f32x16;
typedef __attribute__((ext_vector_type(8))) __bf16 bf16x8;
typedef __attribute__((ext_vector_type(8))) unsigned short u16x8;
typedef __attribute__((ext_vector_type(4))) unsigned short u16x4;

__device__ __forceinline__ u16 f2bf(float f) {
  __bf16 h = (__bf16)f;
  union { __bf16 h; u16 u; } v; v.h = h;
  return v.u;
}

__device__ __forceinline__ float bf2f(u16 u) {
  union { unsigned u; float f; } v; v.u = ((unsigned)u) << 16;
  return v.f;
}

__device__ __forceinline__ u32 pk2(float a, float b) {
  return (u32)f2bf(a) | ((u32)f2bf(b) << 16);
}

__device__ __forceinline__ void async16(const void* g, void* l) {
  __builtin_amdgcn_global_load_lds(
      (const __attribute__((address_space(1))) unsigned int*)g,
      (__attribute__((address_space(3))) unsigned int*)l, 16, 0, 0);
}

__device__ __forceinline__ void barrier_f() {
  asm volatile("" ::: "memory");
  __builtin_amdgcn_s_barrier();
  asm volatile("" ::: "memory");
}

// ---------------- fused prep: x cvt + 4 weight transposes (one launch) ----------------
__device__ __forceinline__ void tcvt_body(const float* __restrict__ W, u16* __restrict__ Wt,
                                          int K, int N, int bx, int by, int t,
                                          float (*tile)[33]) {
  int n0 = bx * 32, k0 = by * 32;
  int tx = t & 31, ty = t >> 5;
#pragma unroll
  for (int i = 0; i < 32; i += 8)
    tile[ty + i][tx] = W[(long)(k0 + ty + i) * N + n0 + tx];
  __syncthreads();
#pragma unroll
  for (int i = 0; i < 32; i += 8)
    Wt[(long)(n0 + ty + i) * K + k0 + tx] = f2bf(tile[tx][ty + i]);
}

__global__ __launch_bounds__(256) void prep_kernel(const float* __restrict__ x,
                                                   u16* __restrict__ xb,
                                                   const float* __restrict__ Wqkv,
                                                   u16* __restrict__ wqkvt,
                                                   const float* __restrict__ Wo,
                                                   u16* __restrict__ wot,
                                                   const float* __restrict__ W1,
                                                   u16* __restrict__ w1t,
                                                   const float* __restrict__ W2,
                                                   u16* __restrict__ w2t) {
  __shared__ float tile[32][33];
  const int b = blockIdx.x, t = threadIdx.x;
  if (b < 8192) {
    long i = (long)b * 256 + t;
    f32x4 v = *(const f32x4*)(x + i * 4);
    u16x4 o;
#pragma unroll
    for (int j = 0; j < 4; j++) o[j] = f2bf(v[j]);
    *(u16x4*)(xb + i * 4) = o;
  } else if (b < 8192 + 3072) {
    int b2 = b - 8192;
    tcvt_body(Wqkv, wqkvt, 1024, 3072, b2 % 96, b2 / 96, t, tile);
  } else if (b < 8192 + 3072 + 1024) {
    int b2 = b - (8192 + 3072);
    tcvt_body(Wo, wot, 1024, 1024, b2 % 32, b2 / 32, t, tile);
  } else if (b < 8192 + 3072 + 1024 + 4096) {
    int b2 = b - (8192 + 3072 + 1024);
    tcvt_body(W1, w1t, 1024, 4096, b2 % 128, b2 / 128, t, tile);
  } else {
    int b2 = b - (8192 + 3072 + 1024 + 4096);
    tcvt_body(W2, w2t, 4096, 1024, b2 % 32, b2 / 32, t, tile);
  }
}

// ======== 8-phase GEMM 256x256, BK=64, 8 waves (2M x 4N), counted vmcnt ========
// QKV: col<1024 -> qb prescaled; [1024,2048) -> kt2 chunked; >=2048 -> vt2 chunked.
// SPLITK: raw bf16 partials to Cp + z*M*N (reduce fused into LN).
template <int BIAS, int GELU, int OBF, int QKV, int SPLITK>
__global__ __launch_bounds__(512, 1) void gemm8p(const u16* __restrict__ A,
                                                 const u16* __restrict__ Bt,
                                                 void* __restrict__ Cp,
                                                 const float* __restrict__ bias,
                                                 u16* __restrict__ kt2,
                                                 u16* __restrict__ vt2,
                                                 int M, int N, int Kst, int Klen) {
  __shared__ u16 As[2][256 * 64];
  __shared__ u16 Bs[2][256 * 64];
  const int t = threadIdx.x, wid = t >> 6, ln = t & 63;
  const int lr = ln & 15, lg = ln >> 4;
  const int wr = wid >> 2, wc = wid & 3;

  const int gx = gridDim.x, gy = gridDim.y;
  const int nwg = gx * gy * gridDim.z;
  const int flat = (blockIdx.z * gy + blockIdx.y) * gx + blockIdx.x;
  const int cpx = nwg >> 3;
  const int swz = (flat & 7) * cpx + (flat >> 3);
  const int sx = swz % gx, rest = swz / gx;
  const int sy = rest % gy, sz = rest / gy;
  const int m0 = sy * 256, n0 = sx * 256;
  const long zo = (long)sz * Klen;
  const int NT = Klen >> 6;

  const int srow = t >> 3;
  const int sch = ((t & 7) ^ (srow & 7)) * 8;
  const u16* gA = A + (long)(m0 + srow) * Kst + zo + sch;
  const u16* gB = Bt + (long)(n0 + srow) * Kst + zo + sch;
  const long KL = Kst;

#define STAGE_A(tt, h)                                                     \
  {                                                                        \
    const u16* s_ = gA + (long)((h) * 128) * KL + (long)(tt) * 64;         \
    char* d_ = (char*)As + ((tt) & 1) * 32768 + (h) * 16384 + wid * 1024;  \
    async16(s_, d_);                                                       \
    async16(s_ + 64 * KL, d_ + 8192);                                      \
  }
#define STAGE_B(tt, h)                                                     \
  {                                                                        \
    const u16* s_ = gB + (long)((h) * 128) * KL + (long)(tt) * 64;         \
    char* d_ = (char*)Bs + ((tt) & 1) * 32768 + (h) * 16384 + wid * 1024;  \
    async16(s_, d_);                                                       \
    async16(s_ + 64 * KL, d_ + 8192);                                      \
  }

  f32x4 acc[8][4] = {};
  const int cx0 = (lg ^ (lr & 7)) * 16;
  const int cx1 = ((4 + lg) ^ (lr & 7)) * 16;

  STAGE_A(0, 0); STAGE_A(0, 1);
  STAGE_B(0, 0); STAGE_B(0, 1);
  STAGE_A(1, 0); STAGE_A(1, 1);

  for (int tK = 0; tK < NT; ++tK) {
    const int cur = tK & 1;
    const char* ldsA = (const char*)As + cur * 32768;
    const char* ldsB = (const char*)Bs + cur * 32768;
    if (tK == NT - 1) {
      asm volatile("s_waitcnt vmcnt(0)" ::: "memory");
    } else {
      asm volatile("s_waitcnt vmcnt(4)" ::: "memory");
    }
    barrier_f();

    bf16x8 aLo[4][2], aHi[4][2], bLo[2][2], bHi[2][2];
#pragma unroll
    for (int mf = 0; mf < 4; mf++) {
      int row = wr * 128 + mf * 16 + lr;
      aLo[mf][0] = *(const bf16x8*)(ldsA + row * 128 + cx0);
      aLo[mf][1] = *(const bf16x8*)(ldsA + row * 128 + cx1);
    }
#pragma unroll
    for (int nf = 0; nf < 2; nf++) {
      int row = wc * 64 + nf * 16 + lr;
      bLo[nf][0] = *(const bf16x8*)(ldsB + row * 128 + cx0);
      bLo[nf][1] = *(const bf16x8*)(ldsB + row * 128 + cx1);
    }
    if (tK + 1 < NT) STAGE_B(tK + 1, 0);
    barrier_f();
    __builtin_amdgcn_s_setprio(1);
#pragma unroll
    for (int mf = 0; mf < 4; mf++)
#pragma unroll
      for (int nf = 0; nf < 2; nf++) {
        acc[mf][nf] = __builtin_amdgcn_mfma_f32_16x16x32_bf16(aLo[mf][0], bLo[nf][0], acc[mf][nf], 0, 0, 0);
        acc[mf][nf] = __builtin_amdgcn_mfma_f32_16x16x32_bf16(aLo[mf][1], bLo[nf][1], acc[mf][nf], 0, 0, 0);
      }
    __builtin_amdgcn_s_setprio(0);
    barrier_f();

#pragma unroll
    for (int mf = 0; mf < 4; mf++) {
      int row = wr * 128 + (mf + 4) * 16 + lr;
      aHi[mf][0] = *(const bf16x8*)(ldsA + row * 128 + cx0);
      aHi[mf][1] = *(const bf16x8*)(ldsA + row * 128 + cx1);
    }
    if (tK + 1 < NT) STAGE_B(tK + 1, 1);
    barrier_f();
    __builtin_amdgcn_s_setprio(1);
#pragma unroll
    for (int mf = 0; mf < 4; mf++)
#pragma unroll
      for (int nf = 0; nf < 2; nf++) {
        acc[mf + 4][nf] = __builtin_amdgcn_mfma_f32_16x16x32_bf16(aHi[mf][0], bLo[nf][0], acc[mf + 4][nf], 0, 0, 0);
        acc[mf + 4][nf] = __builtin_amdgcn_mfma_f32_16x16x32_bf16(aHi[mf][1], bLo[nf][1], acc[mf + 4][nf], 0, 0, 0);
      }
    __builtin_amdgcn_s_setprio(0);
    barrier_f();

#pragma unroll
    for (int nf = 0; nf < 2; nf++) {
      int row = wc * 64 + (nf + 2) * 16 + lr;
      bHi[nf][0] = *(const bf16x8*)(ldsB + row * 128 + cx0);
      bHi[nf][1] = *(const bf16x8*)(ldsB + row * 128 + cx1);
    }
    if (tK + 2 < NT) STAGE_A(tK + 2, 0);
    barrier_f();
    __builtin_amdgcn_s_setprio(1);
#pragma unroll
    for (int mf = 0; mf < 4; mf++)
#pragma unroll
      for (int nf = 0; nf < 2; nf++) {
        acc[mf][nf + 2] = __builtin_amdgcn_mfma_f32_16x16x32_bf16(aLo[mf][0], bHi[nf][0], acc[mf][nf + 2], 0, 0, 0);
        acc[mf][nf + 2] = __builtin_amdgcn_mfma_f32_16x16x32_bf16(aLo[mf][1], bHi[nf][1], acc[mf][nf + 2], 0, 0, 0);
      }
    __builtin_amdgcn_s_setprio(0);
    barrier_f();

    if (tK + 2 < NT) STAGE_A(tK + 2, 1);
    barrier_f();
    __builtin_amdgcn_s_setprio(1);
#pragma unroll
    for (int mf = 0; mf < 4; mf++)
#pragma unroll
      for (int nf = 0; nf < 2; nf++) {
        acc[mf + 4][nf + 2] = __builtin_amdgcn_mfma_f32_16x16x32_bf16(aHi[mf][0], bHi[nf][0], acc[mf + 4][nf + 2], 0, 0, 0);
        acc[mf + 4][nf + 2] = __builtin_amdgcn_mfma_f32_16x16x32_bf16(aHi[mf][1], bHi[nf][1], acc[mf + 4][nf + 2], 0, 0, 0);
      }
    __builtin_amdgcn_s_setprio(0);
    barrier_f();
  }
#undef STAGE_A
#undef STAGE_B

  u16* const Cu = (u16*)Cp + (SPLITK ? (long)sz * M * N : 0);
#pragma unroll
  for (int mf = 0; mf < 8; mf++) {
    int rbase = m0 + wr * 128 + mf * 16 + lg * 4;
#pragma unroll
    for (int nf = 0; nf < 4; nf++) {
      int col = n0 + wc * 64 + nf * 16 + lr;
      float bv = BIAS ? bias[col] : 0.f;
      if (QKV) {
        int bq = rbase >> 11;
        if (col < 1024) {
#pragma unroll
          for (int r = 0; r < 4; r++)
            ((u16*)Cp)[(long)(rbase + r) * 1024 + col] = f2bf(acc[mf][nf][r] * 0.18033688011112043f);
        } else if (col < 2048) {
          int hd = col - 1024, h_ = hd >> 6, d = hd & 63;
#pragma unroll
          for (int r = 0; r < 4; r++) {
            int key = (rbase + r) & 2047;
            kt2[((((long)(bq * 16 + h_) * 32 + (key >> 6)) * 8 + (d >> 3)) * 64 + (key & 63)) * 8 + (d & 7)] =
                f2bf(acc[mf][nf][r]);
          }
        } else {
          int hd = col - 2048, h_ = hd >> 6, d = hd & 63;
          int key0 = rbase & 2047;
          u16x4 o4;
#pragma unroll
          for (int r = 0; r < 4; r++) o4[r] = f2bf(acc[mf][nf][r]);
          *(u16x4*)&vt2[((((long)(bq * 16 + h_) * 32 + (key0 >> 6)) * 8 + ((key0 >> 3) & 7)) * 64 + d) * 8 + (key0 & 7)] = o4;
        }
      } else if (SPLITK) {
#pragma unroll
        for (int r = 0; r < 4; r++)
          Cu[(long)(rbase + r) * N + col] = f2bf(acc[mf][nf][r]);
      } else {
#pragma unroll
        for (int r = 0; r < 4; r++) {
          float v = acc[mf][nf][r] + bv;
          if (GELU) v = v / (1.f + __expf(-1.702f * v));
          if (OBF) ((u16*)Cp)[(long)(rbase + r) * N + col] = f2bf(v);
          else ((float*)Cp)[(long)(rbase + r) * N + col] = v;
        }
      }
    }
  }
}

// ---------------- flash attention v5: 32x32 MFMA, KVBLK=128, permlane32_swap P ----------------
// qb: [8192][1024] prescaled Q. kt2/vt2: chunk-major tiles (64-key tile = 4KB contiguous).
__global__ __launch_bounds__(512, 4) void attn_kernel(const u16* __restrict__ qb,
                                                      const u16* __restrict__ kt2,
                                                      const u16* __restrict__ vt2,
                                                      u16* __restrict__ out) {
  const int bh = blockIdx.y, h = bh & 15;
  const int q0 = blockIdx.x * 256;
  const int t = threadIdx.x, wv = t >> 6, ln = t & 63;
  const int lq = ln & 31, hi = ln >> 5;
  __shared__ u16 Ks[2][8192];   // 2 x 16KB: tile-pair (128 keys), [sub][dchunk8][key64][8]
  __shared__ u16 Vs[2][8192];   // 2 x 16KB: [sub][keychunk8][d64][8]   (64KB total)
  const long tok0 = (long)(bh >> 4) * 2048;

  // Q B-frags: col=q=lq, k(d) = c*16 + hi*8 + j
  bf16x8 bQ[4];
  {
    long row = tok0 + q0 + wv * 32 + lq;
    const u16* qp = &qb[row * 1024 + h * 64 + hi * 8];
#pragma unroll
    for (int c = 0; c < 4; c++) bQ[c] = *(const bf16x8*)(qp + c * 16);
  }

  // staging: threads 0-255 stage K, 256-511 stage V; 4 async16/thread per tile-pair
  const int isK = (t < 256);
  const int tt = t & 255;
  const u16* gS = (isK ? kt2 : vt2) + (long)bh * 131072 + tt * 8;
  char* const dS = (isK ? (char*)&Ks[0][0] : (char*)&Vs[0][0]) + (wv & 3) * 1024;

  f32x16 accO0 = {}, accO1 = {}, accL = {};

  bf16x8 aOnes;
  {
    union { u16x8 u; bf16x8 b; } ou;
#pragma unroll
    for (int j = 0; j < 8; j++) ou.u[j] = 0x3F80;
    aOnes = ou.b;
  }

  // prologue: tile-pair 0 into buffer 0
#pragma unroll
  for (int i = 0; i < 4; i++) async16(gS + i * 2048, dS + i * 4096);
  gS += 8192;

  for (int it = 0; it < 16; ++it) {
    const int cur = it & 1;
    if (it < 15) {
      char* nS = dS + (cur ^ 1) * 16384;
#pragma unroll
      for (int i = 0; i < 4; i++) async16(gS + i * 2048, nS + i * 4096);
      gS += 8192;
      asm volatile("s_waitcnt vmcnt(4)" ::: "memory");
    } else {
      asm volatile("s_waitcnt vmcnt(0)" ::: "memory");
    }
    __builtin_amdgcn_s_barrier();
    __builtin_amdgcn_sched_barrier(0);

#pragma unroll
    for (int sub = 0; sub < 2; ++sub) {
      const u16* Kc = &Ks[cur][sub * 4096];
      const u16* Vc = &Vs[cur][sub * 4096];

      // ---- S^T = K Q^T (2 key-blocks of 32), exp2, pack P into B-frags ----
      u32 frag[4][4];
#pragma unroll
      for (int kb = 0; kb < 2; kb++) {
        f32x16 s = {};
        __builtin_amdgcn_s_setprio(1);
#pragma unroll
        for (int c = 0; c < 4; c++) {
          bf16x8 aK = *(const bf16x8*)&Kc[((c * 2 + hi) * 64 + kb * 32 + lq) * 8];
          s = __builtin_amdgcn_mfma_f32_32x32x16_bf16(aK, bQ[c], s, 0, 0, 0);
        }
        __builtin_amdgcn_s_setprio(0);
        float pv[16];
#pragma unroll
        for (int r = 0; r < 16; r++) pv[r] = exp2f(s[r]);
#pragma unroll
        for (int cc = 0; cc < 2; cc++) {
          // lo-half regs (rows for hi=0), hi-half regs (rows for hi=1)
          u32 a0 = pk2(pv[8 * cc + 0], pv[8 * cc + 1]);
          u32 a1 = pk2(pv[8 * cc + 2], pv[8 * cc + 3]);
          u32 b0 = pk2(pv[8 * cc + 4], pv[8 * cc + 5]);
          u32 b1 = pk2(pv[8 * cc + 6], pv[8 * cc + 7]);
          // v_permlane32_swap_b32: a.hi <-> b.lo  => a = frag(lo-own / hi-partner),
          // b = frag(lo-partner / hi-own) — replaces 4 shfl + 4 select per pair.
          asm("v_permlane32_swap_b32 %0, %1" : "+v"(a0), "+v"(b0));
          asm("v_permlane32_swap_b32 %0, %1" : "+v"(a1), "+v"(b1));
          frag[kb * 2 + cc][0] = a0;
          frag[kb * 2 + cc][1] = a1;
          frag[kb * 2 + cc][2] = b0;
          frag[kb * 2 + cc][3] = b1;
        }
      }

      // ---- O^T += V^T P^T ; L += 1^T P^T (ones-MFMA row-sum) ----
      __builtin_amdgcn_s_setprio(1);
#pragma unroll
      for (int c2 = 0; c2 < 4; c2++) {
        union { u32 u[4]; bf16x8 v; } pb;
        pb.u[0] = frag[c2][0]; pb.u[1] = frag[c2][1];
        pb.u[2] = frag[c2][2]; pb.u[3] = frag[c2][3];
        bf16x8 aV0 = *(const bf16x8*)&Vc[((c2 * 2 + hi) * 64 + lq) * 8];
        bf16x8 aV1 = *(const bf16x8*)&Vc[((c2 * 2 + hi) * 64 + 32 + lq) * 8];
        accL = __builtin_amdgcn_mfma_f32_32x32x16_bf16(aOnes, pb.v, accL, 0, 0, 0);
        accO0 = __builtin_amdgcn_mfma_f32_32x32x16_bf16(aV0, pb.v, accO0, 0, 0, 0);
        accO1 = __builtin_amdgcn_mfma_f32_32x32x16_bf16(aV1, pb.v, accO1, 0, 0, 0);
      }
      __builtin_amdgcn_s_setprio(0);
    }
    __builtin_amdgcn_s_barrier();
    __builtin_amdgcn_sched_barrier(0);
  }

  // accL: every reg = sum over all 2048 keys for col q=lq -> no cross-lane reduce
  float inv = 1.f / accL[0];
  long tq = tok0 + q0 + wv * 32 + lq;
  u16* op = &out[tq * 1024 + h * 64 + hi * 4];
#pragma unroll
  for (int qd = 0; qd < 4; qd++) {
    u16x4 o4, o5;
#pragma unroll
    for (int j = 0; j < 4; j++) {
      o4[j] = f2bf(accO0[qd * 4 + j] * inv);
      o5[j] = f2bf(accO1[qd * 4 + j] * inv);
    }
    *(u16x4*)(op + qd * 8) = o4;
    *(u16x4*)(op + 32 + qd * 8) = o5;
  }
}

// ---------------- fused add + layernorm: v = x + p0 + p1 + bias ----------------
// XBF: x input is bf16. OF32: write f32 out; else write bf16 out.
template <int XBF, int OF32>
__global__ __launch_bounds__(256) void ln_kernel(const void* __restrict__ xin,
                                                 const u16* __restrict__ p0,
                                                 const u16* __restrict__ p1,
                                                 const float* __restrict__ bias,
                                                 const float* __restrict__ g,
                                                 const float* __restrict__ be,
                                                 float* __restrict__ of,
                                                 u16* __restrict__ ob) {
  int row = blockIdx.x, t = threadIdx.x;
  long base = (long)row * 1024 + t * 4;
  f32x4 a;
  if (XBF) {
    u16x4 xa = *((const u16x4*)xin + row * 256 + t);
#pragma unroll
    for (int j = 0; j < 4; j++) a[j] = bf2f(xa[j]);
  } else {
    a = *((const f32x4*)xin + row * 256 + t);
  }
  u16x4 u0 = *(const u16x4*)(p0 + base);
  u16x4 u1 = *(const u16x4*)(p1 + base);
  f32x4 bb4 = *(const f32x4*)(bias + t * 4);
  f32x4 v;
#pragma unroll
  for (int j = 0; j < 4; j++) v[j] = a[j] + bf2f(u0[j]) + bf2f(u1[j]) + bb4[j];
  float s = v[0] + v[1] + v[2] + v[3];
  float ss = v[0] * v[0] + v[1] * v[1] + v[2] * v[2] + v[3] * v[3];
#pragma unroll
  for (int o = 1; o < 64; o <<= 1) { s += __shfl_xor(s, o); ss += __shfl_xor(ss, o); }
  __shared__ float sm[8];
  if ((t & 63) == 0) { sm[t >> 6] = s; sm[4 + (t >> 6)] = ss; }
  __syncthreads();
  s = sm[0] + sm[1] + sm[2] + sm[3];
  ss = sm[4] + sm[5] + sm[6] + sm[7];
  float mu = s * 0.0009765625f;
  float var = ss * 0.0009765625f - mu * mu;
  float inv = rsqrtf(var + 1e-5f);
  f32x4 gg = *(const f32x4*)(g + t * 4);
  f32x4 bb = *(const f32x4*)(be + t * 4);
  f32x4 y;
#pragma unroll
  for (int j = 0; j < 4; j++) y[j] = (v[j] - mu) * inv * gg[j] + bb[j];
  if (OF32) {
    *(f32x4*)(of + base) = y;
  } else {
    u16x4 o4;
#pragma unroll
    for (int j = 0; j < 4; j++) o4[j] = f2bf(y[j]);
    *(u16x4*)(ob + base) = o4;
  }
}

// ---------------- launch ----------------
extern "C" void kernel_launch(void* const* d_in, const int* in_sizes, int n_in,
                              void* d_out, int out_size, void* d_ws, size_t ws_size,
                              hipStream_t stream) {
  const float* x = (const float*)d_in[0];
  const float* Wqkv = (const float*)d_in[1];
  const float* Wo = (const float*)d_in[2];
  const float* bo = (const float*)d_in[3];
  const float* g1 = (const float*)d_in[4];
  const float* be1 = (const float*)d_in[5];
  const float* W1 = (const float*)d_in[6];
  const float* b1 = (const float*)d_in[7];
  const float* W2 = (const float*)d_in[8];
  const float* b2 = (const float*)d_in[9];
  const float* g2 = (const float*)d_in[10];
  const float* be2 = (const float*)d_in[11];
  float* out = (float*)d_out;
  char* ws = (char*)d_ws;

  // workspace layout (bytes), lifetime-overlaid (~159.4MB):
  u16* xb = (u16*)(ws + 0);                 // 16.78M [prep -> qkv]
  u16* qb = (u16*)(ws + 16777216);          // 16.78M [qkv -> attn]
  u16* kt2b = (u16*)(ws + 33554432);        // 16.78M [qkv -> attn]
  u16* vt2b = (u16*)(ws + 50331648);        // 16.78M [qkv -> attn]
  u16* h1b = (u16*)(ws + 0);                // 67.11M [mlp1 -> mlp2] reuses xb+qb+kt2+vt2
  u16* attnb = (u16*)(ws + 67108864);       // 16.78M [attn -> proj]
  u16* x1b = (u16*)(ws + 83886080);         // 16.78M [ln1 -> ln2]
  u16* pp = (u16*)(ws + 100663296);         // 33.55M [proj partials -> ln1]
  u16* ffp = (u16*)(ws + 100663296);        // 33.55M [mlp2 partials -> ln2] reuses pp
  u16* wqkvt = (u16*)(ws + 134217728);      // 6.29M
  u16* wot = (u16*)(ws + 140509184);        // 2.10M
  u16* w1t = (u16*)(ws + 142606336);        // 8.39M
  u16* w2t = (u16*)(ws + 150994944);        // 8.39M (end 159.4M)

  // fused prep: x cvt + all 4 weight transposes (1 launch instead of 5)
  prep_kernel<<<20480, 256, 0, stream>>>(x, xb, Wqkv, wqkvt, Wo, wot, W1, w1t, W2, w2t);
  // qkv = x @ Wqkv: Q prescaled -> qb; K -> kt2 chunked; V -> vt2 chunked
  gemm8p<0, 0, 0, 1, 0><<<dim3(12, 32, 1), 512, 0, stream>>>(
      xb, wqkvt, qb, nullptr, kt2b, vt2b, 8192, 3072, 1024, 1024);
  attn_kernel<<<dim3(8, 64), 512, 0, stream>>>(qb, kt2b, vt2b, attnb);
  // proj partials = attn @ Wo (split-K x2, bf16 partials; bias+reduce in LN1)
  gemm8p<0, 0, 0, 0, 1><<<dim3(4, 32, 2), 512, 0, stream>>>(
      attnb, wot, pp, nullptr, nullptr, nullptr, 8192, 1024, 1024, 512);
  // x1 = LN(x + pp0 + pp1 + bo) -> bf16 only
  ln_kernel<0, 0><<<8192, 256, 0, stream>>>(x, pp, pp + (long)8192 * 1024, bo,
                                            g1, be1, nullptr, x1b);
  // h1 = gelu(x1 @ W1 + b1)
  gemm8p<1, 1, 1, 0, 0><<<dim3(16, 32, 1), 512, 0, stream>>>(
      x1b, w1t, h1b, b1, nullptr, nullptr, 8192, 4096, 1024, 1024);
  // ff partials = h1 @ W2 (split-K x2, bf16 partials; bias+reduce in LN2)
  gemm8p<0, 0, 0, 0, 1><<<dim3(4, 32, 2), 512, 0, stream>>>(
      h1b, w2t, ffp, nullptr, nullptr, nullptr, 8192, 1024, 4096, 2048);
  // out = LN(x1 + ffp0 + ffp1 + b2) -> f32
  ln_kernel<1, 1><<<8192, 256, 0, stream>>>(x1b, ffp, ffp + (long)8192 * 1024, b2,
                                            g2, be2, out, nullptr);
}

// Round 13
// 384.831 us; speedup vs baseline: 1.0367x; 1.0069x over previous
//
#include <hip/hip_runtime.h>

typedef unsigned short u16;
typedef unsigned int u32;
typedef __attribute__((ext_vector_type(4))) float f32x4;
typedef __attribute__((ext_vector_type(16))) float f32x16;
typedef __attribute__((ext_vector_type(8))) __bf16 bf16x8;
typedef __attribute__((ext_vector_type(8))) unsigned short u16x8;
typedef __attribute__((ext_vector_type(4))) unsigned short u16x4;

__device__ __forceinline__ u16 f2bf(float f) {
  __bf16 h = (__bf16)f;
  union { __bf16 h; u16 u; } v; v.h = h;
  return v.u;
}

__device__ __forceinline__ float bf2f(u16 u) {
  union { unsigned u; float f; } v; v.u = ((unsigned)u) << 16;
  return v.f;
}

__device__ __forceinline__ u32 pk2(float a, float b) {
  return (u32)f2bf(a) | ((u32)f2bf(b) << 16);
}

__device__ __forceinline__ void async16(const void* g, void* l) {
  __builtin_amdgcn_global_load_lds(
      (const __attribute__((address_space(1))) unsigned int*)g,
      (__attribute__((address_space(3))) unsigned int*)l, 16, 0, 0);
}

__device__ __forceinline__ void barrier_f() {
  asm volatile("" ::: "memory");
  __builtin_amdgcn_s_barrier();
  asm volatile("" ::: "memory");
}

// ---------------- fused prep: x cvt + 4 weight transposes (one launch) ----------------
__device__ __forceinline__ void tcvt_body(const float* __restrict__ W, u16* __restrict__ Wt,
                                          int K, int N, int bx, int by, int t,
                                          float (*tile)[33]) {
  int n0 = bx * 32, k0 = by * 32;
  int tx = t & 31, ty = t >> 5;
#pragma unroll
  for (int i = 0; i < 32; i += 8)
    tile[ty + i][tx] = W[(long)(k0 + ty + i) * N + n0 + tx];
  __syncthreads();
#pragma unroll
  for (int i = 0; i < 32; i += 8)
    Wt[(long)(n0 + ty + i) * K + k0 + tx] = f2bf(tile[tx][ty + i]);
}

__global__ __launch_bounds__(256) void prep_kernel(const float* __restrict__ x,
                                                   u16* __restrict__ xb,
                                                   const float* __restrict__ Wqkv,
                                                   u16* __restrict__ wqkvt,
                                                   const float* __restrict__ Wo,
                                                   u16* __restrict__ wot,
                                                   const float* __restrict__ W1,
                                                   u16* __restrict__ w1t,
                                                   const float* __restrict__ W2,
                                                   u16* __restrict__ w2t) {
  __shared__ float tile[32][33];
  const int b = blockIdx.x, t = threadIdx.x;
  if (b < 8192) {
    long i = (long)b * 256 + t;
    f32x4 v = *(const f32x4*)(x + i * 4);
    u16x4 o;
#pragma unroll
    for (int j = 0; j < 4; j++) o[j] = f2bf(v[j]);
    *(u16x4*)(xb + i * 4) = o;
  } else if (b < 8192 + 3072) {
    int b2 = b - 8192;
    tcvt_body(Wqkv, wqkvt, 1024, 3072, b2 % 96, b2 / 96, t, tile);
  } else if (b < 8192 + 3072 + 1024) {
    int b2 = b - (8192 + 3072);
    tcvt_body(Wo, wot, 1024, 1024, b2 % 32, b2 / 32, t, tile);
  } else if (b < 8192 + 3072 + 1024 + 4096) {
    int b2 = b - (8192 + 3072 + 1024);
    tcvt_body(W1, w1t, 1024, 4096, b2 % 128, b2 / 128, t, tile);
  } else {
    int b2 = b - (8192 + 3072 + 1024 + 4096);
    tcvt_body(W2, w2t, 4096, 1024, b2 % 32, b2 / 32, t, tile);
  }
}

// ======== 8-phase GEMM 256x256, BK=64, 8 waves (2M x 4N), counted vmcnt ========
// QKV: col<1024 -> qb prescaled; [1024,2048) -> kt2 chunked; >=2048 -> vt2 chunked.
// SPLITK: raw bf16 partials to Cp + z*M*N (reduce fused into LN).
template <int BIAS, int GELU, int OBF, int QKV, int SPLITK>
__global__ __launch_bounds__(512, 1) void gemm8p(const u16* __restrict__ A,
                                                 const u16* __restrict__ Bt,
                                                 void* __restrict__ Cp,
                                                 const float* __restrict__ bias,
                                                 u16* __restrict__ kt2,
                                                 u16* __restrict__ vt2,
                                                 int M, int N, int Kst, int Klen) {
  __shared__ u16 As[2][256 * 64];
  __shared__ u16 Bs[2][256 * 64];
  const int t = threadIdx.x, wid = t >> 6, ln = t & 63;
  const int lr = ln & 15, lg = ln >> 4;
  const int wr = wid >> 2, wc = wid & 3;

  const int gx = gridDim.x, gy = gridDim.y;
  const int nwg = gx * gy * gridDim.z;
  const int flat = (blockIdx.z * gy + blockIdx.y) * gx + blockIdx.x;
  const int cpx = nwg >> 3;
  const int swz = (flat & 7) * cpx + (flat >> 3);
  const int sx = swz % gx, rest = swz / gx;
  const int sy = rest % gy, sz = rest / gy;
  const int m0 = sy * 256, n0 = sx * 256;
  const long zo = (long)sz * Klen;
  const int NT = Klen >> 6;

  const int srow = t >> 3;
  const int sch = ((t & 7) ^ (srow & 7)) * 8;
  const u16* gA = A + (long)(m0 + srow) * Kst + zo + sch;
  const u16* gB = Bt + (long)(n0 + srow) * Kst + zo + sch;
  const long KL = Kst;

#define STAGE_A(tt, h)                                                     \
  {                                                                        \
    const u16* s_ = gA + (long)((h) * 128) * KL + (long)(tt) * 64;         \
    char* d_ = (char*)As + ((tt) & 1) * 32768 + (h) * 16384 + wid * 1024;  \
    async16(s_, d_);                                                       \
    async16(s_ + 64 * KL, d_ + 8192);                                      \
  }
#define STAGE_B(tt, h)                                                     \
  {                                                                        \
    const u16* s_ = gB + (long)((h) * 128) * KL + (long)(tt) * 64;         \
    char* d_ = (char*)Bs + ((tt) & 1) * 32768 + (h) * 16384 + wid * 1024;  \
    async16(s_, d_);                                                       \
    async16(s_ + 64 * KL, d_ + 8192);                                      \
  }

  f32x4 acc[8][4] = {};
  const int cx0 = (lg ^ (lr & 7)) * 16;
  const int cx1 = ((4 + lg) ^ (lr & 7)) * 16;

  STAGE_A(0, 0); STAGE_A(0, 1);
  STAGE_B(0, 0); STAGE_B(0, 1);
  STAGE_A(1, 0); STAGE_A(1, 1);

  for (int tK = 0; tK < NT; ++tK) {
    const int cur = tK & 1;
    const char* ldsA = (const char*)As + cur * 32768;
    const char* ldsB = (const char*)Bs + cur * 32768;
    if (tK == NT - 1) {
      asm volatile("s_waitcnt vmcnt(0)" ::: "memory");
    } else {
      asm volatile("s_waitcnt vmcnt(4)" ::: "memory");
    }
    barrier_f();

    bf16x8 aLo[4][2], aHi[4][2], bLo[2][2], bHi[2][2];
#pragma unroll
    for (int mf = 0; mf < 4; mf++) {
      int row = wr * 128 + mf * 16 + lr;
      aLo[mf][0] = *(const bf16x8*)(ldsA + row * 128 + cx0);
      aLo[mf][1] = *(const bf16x8*)(ldsA + row * 128 + cx1);
    }
#pragma unroll
    for (int nf = 0; nf < 2; nf++) {
      int row = wc * 64 + nf * 16 + lr;
      bLo[nf][0] = *(const bf16x8*)(ldsB + row * 128 + cx0);
      bLo[nf][1] = *(const bf16x8*)(ldsB + row * 128 + cx1);
    }
    if (tK + 1 < NT) STAGE_B(tK + 1, 0);
    barrier_f();
    __builtin_amdgcn_s_setprio(1);
#pragma unroll
    for (int mf = 0; mf < 4; mf++)
#pragma unroll
      for (int nf = 0; nf < 2; nf++) {
        acc[mf][nf] = __builtin_amdgcn_mfma_f32_16x16x32_bf16(aLo[mf][0], bLo[nf][0], acc[mf][nf], 0, 0, 0);
        acc[mf][nf] = __builtin_amdgcn_mfma_f32_16x16x32_bf16(aLo[mf][1], bLo[nf][1], acc[mf][nf], 0, 0, 0);
      }
    __builtin_amdgcn_s_setprio(0);
    barrier_f();

#pragma unroll
    for (int mf = 0; mf < 4; mf++) {
      int row = wr * 128 + (mf + 4) * 16 + lr;
      aHi[mf][0] = *(const bf16x8*)(ldsA + row * 128 + cx0);
      aHi[mf][1] = *(const bf16x8*)(ldsA + row * 128 + cx1);
    }
    if (tK + 1 < NT) STAGE_B(tK + 1, 1);
    barrier_f();
    __builtin_amdgcn_s_setprio(1);
#pragma unroll
    for (int mf = 0; mf < 4; mf++)
#pragma unroll
      for (int nf = 0; nf < 2; nf++) {
        acc[mf + 4][nf] = __builtin_amdgcn_mfma_f32_16x16x32_bf16(aHi[mf][0], bLo[nf][0], acc[mf + 4][nf], 0, 0, 0);
        acc[mf + 4][nf] = __builtin_amdgcn_mfma_f32_16x16x32_bf16(aHi[mf][1], bLo[nf][1], acc[mf + 4][nf], 0, 0, 0);
      }
    __builtin_amdgcn_s_setprio(0);
    barrier_f();

#pragma unroll
    for (int nf = 0; nf < 2; nf++) {
      int row = wc * 64 + (nf + 2) * 16 + lr;
      bHi[nf][0] = *(const bf16x8*)(ldsB + row * 128 + cx0);
      bHi[nf][1] = *(const bf16x8*)(ldsB + row * 128 + cx1);
    }
    if (tK + 2 < NT) STAGE_A(tK + 2, 0);
    barrier_f();
    __builtin_amdgcn_s_setprio(1);
#pragma unroll
    for (int mf = 0; mf < 4; mf++)
#pragma unroll
      for (int nf = 0; nf < 2; nf++) {
        acc[mf][nf + 2] = __builtin_amdgcn_mfma_f32_16x16x32_bf16(aLo[mf][0], bHi[nf][0], acc[mf][nf + 2], 0, 0, 0);
        acc[mf][nf + 2] = __builtin_amdgcn_mfma_f32_16x16x32_bf16(aLo[mf][1], bHi[nf][1], acc[mf][nf + 2], 0, 0, 0);
      }
    __builtin_amdgcn_s_setprio(0);
    barrier_f();

    if (tK + 2 < NT) STAGE_A(tK + 2, 1);
    barrier_f();
    __builtin_amdgcn_s_setprio(1);
#pragma unroll
    for (int mf = 0; mf < 4; mf++)
#pragma unroll
      for (int nf = 0; nf < 2; nf++) {
        acc[mf + 4][nf + 2] = __builtin_amdgcn_mfma_f32_16x16x32_bf16(aHi[mf][0], bHi[nf][0], acc[mf + 4][nf + 2], 0, 0, 0);
        acc[mf + 4][nf + 2] = __builtin_amdgcn_mfma_f32_16x16x32_bf16(aHi[mf][1], bHi[nf][1], acc[mf + 4][nf + 2], 0, 0, 0);
      }
    __builtin_amdgcn_s_setprio(0);
    barrier_f();
  }
#undef STAGE_A
#undef STAGE_B

  u16* const Cu = (u16*)Cp + (SPLITK ? (long)sz * M * N : 0);
#pragma unroll
  for (int mf = 0; mf < 8; mf++) {
    int rbase = m0 + wr * 128 + mf * 16 + lg * 4;
#pragma unroll
    for (int nf = 0; nf < 4; nf++) {
      int col = n0 + wc * 64 + nf * 16 + lr;
      float bv = BIAS ? bias[col] : 0.f;
      if (QKV) {
        int bq = rbase >> 11;
        if (col < 1024) {
#pragma unroll
          for (int r = 0; r < 4; r++)
            ((u16*)Cp)[(long)(rbase + r) * 1024 + col] = f2bf(acc[mf][nf][r] * 0.18033688011112043f);
        } else if (col < 2048) {
          int hd = col - 1024, h_ = hd >> 6, d = hd & 63;
#pragma unroll
          for (int r = 0; r < 4; r++) {
            int key = (rbase + r) & 2047;
            kt2[((((long)(bq * 16 + h_) * 32 + (key >> 6)) * 8 + (d >> 3)) * 64 + (key & 63)) * 8 + (d & 7)] =
                f2bf(acc[mf][nf][r]);
          }
        } else {
          int hd = col - 2048, h_ = hd >> 6, d = hd & 63;
          int key0 = rbase & 2047;
          u16x4 o4;
#pragma unroll
          for (int r = 0; r < 4; r++) o4[r] = f2bf(acc[mf][nf][r]);
          *(u16x4*)&vt2[((((long)(bq * 16 + h_) * 32 + (key0 >> 6)) * 8 + ((key0 >> 3) & 7)) * 64 + d) * 8 + (key0 & 7)] = o4;
        }
      } else if (SPLITK) {
#pragma unroll
        for (int r = 0; r < 4; r++)
          Cu[(long)(rbase + r) * N + col] = f2bf(acc[mf][nf][r]);
      } else {
#pragma unroll
        for (int r = 0; r < 4; r++) {
          float v = acc[mf][nf][r] + bv;
          if (GELU) v = v / (1.f + __expf(-1.702f * v));
          if (OBF) ((u16*)Cp)[(long)(rbase + r) * N + col] = f2bf(v);
          else ((float*)Cp)[(long)(rbase + r) * N + col] = v;
        }
      }
    }
  }
}

// ---------------- flash attention v6: 32x32 MFMA, KVBLK=128, XCD-local K/V ----------------
// Grid: 512 1-D blocks. bh = flat mod-8-interleaved so all q-blocks of one bh land
// on one XCD (per-XCD K/V working set = 8 bh x 512KB = 4MB = L2 size).
__global__ __launch_bounds__(512, 4) void attn_kernel(const u16* __restrict__ qb,
                                                      const u16* __restrict__ kt2,
                                                      const u16* __restrict__ vt2,
                                                      u16* __restrict__ out) {
  const int flat = blockIdx.x;
  const int bh_low = flat & 7, rest = flat >> 3;
  const int qi = rest & 7;
  const int bh = ((rest >> 3) << 3) | bh_low;
  const int h = bh & 15;
  const int q0 = qi * 256;
  const int t = threadIdx.x, wv = t >> 6, ln = t & 63;
  const int lq = ln & 31, hi = ln >> 5;
  __shared__ u16 Ks[2][8192];   // 2 x 16KB: tile-pair (128 keys), [sub][dchunk8][key64][8]
  __shared__ u16 Vs[2][8192];   // 2 x 16KB: [sub][keychunk8][d64][8]   (64KB total)
  const long tok0 = (long)(bh >> 4) * 2048;

  // Q B-frags: col=q=lq, k(d) = c*16 + hi*8 + j
  bf16x8 bQ[4];
  {
    long row = tok0 + q0 + wv * 32 + lq;
    const u16* qp = &qb[row * 1024 + h * 64 + hi * 8];
#pragma unroll
    for (int c = 0; c < 4; c++) bQ[c] = *(const bf16x8*)(qp + c * 16);
  }

  // staging: threads 0-255 stage K, 256-511 stage V; 4 async16/thread per tile-pair
  const int isK = (t < 256);
  const int tt = t & 255;
  const u16* gS = (isK ? kt2 : vt2) + (long)bh * 131072 + tt * 8;
  char* const dS = (isK ? (char*)&Ks[0][0] : (char*)&Vs[0][0]) + (wv & 3) * 1024;

  f32x16 accO0 = {}, accO1 = {}, accL = {};

  bf16x8 aOnes;
  {
    union { u16x8 u; bf16x8 b; } ou;
#pragma unroll
    for (int j = 0; j < 8; j++) ou.u[j] = 0x3F80;
    aOnes = ou.b;
  }

  // prologue: tile-pair 0 into buffer 0
#pragma unroll
  for (int i = 0; i < 4; i++) async16(gS + i * 2048, dS + i * 4096);
  gS += 8192;

  for (int it = 0; it < 16; ++it) {
    const int cur = it & 1;
    if (it < 15) {
      char* nS = dS + (cur ^ 1) * 16384;
#pragma unroll
      for (int i = 0; i < 4; i++) async16(gS + i * 2048, nS + i * 4096);
      gS += 8192;
      asm volatile("s_waitcnt vmcnt(4)" ::: "memory");
    } else {
      asm volatile("s_waitcnt vmcnt(0)" ::: "memory");
    }
    __builtin_amdgcn_s_barrier();
    __builtin_amdgcn_sched_barrier(0);

#pragma unroll
    for (int sub = 0; sub < 2; ++sub) {
      const u16* Kc = &Ks[cur][sub * 4096];
      const u16* Vc = &Vs[cur][sub * 4096];

      // ---- S^T = K Q^T (2 key-blocks of 32), exp2, pack P into B-frags ----
      u32 frag[4][4];
#pragma unroll
      for (int kb = 0; kb < 2; kb++) {
        f32x16 s = {};
        __builtin_amdgcn_s_setprio(1);
#pragma unroll
        for (int c = 0; c < 4; c++) {
          bf16x8 aK = *(const bf16x8*)&Kc[((c * 2 + hi) * 64 + kb * 32 + lq) * 8];
          s = __builtin_amdgcn_mfma_f32_32x32x16_bf16(aK, bQ[c], s, 0, 0, 0);
        }
        __builtin_amdgcn_s_setprio(0);
        float pv[16];
#pragma unroll
        for (int r = 0; r < 16; r++) pv[r] = exp2f(s[r]);
#pragma unroll
        for (int cc = 0; cc < 2; cc++) {
          u32 a0 = pk2(pv[8 * cc + 0], pv[8 * cc + 1]);
          u32 a1 = pk2(pv[8 * cc + 2], pv[8 * cc + 3]);
          u32 b0 = pk2(pv[8 * cc + 4], pv[8 * cc + 5]);
          u32 b1 = pk2(pv[8 * cc + 6], pv[8 * cc + 7]);
          asm("v_permlane32_swap_b32 %0, %1" : "+v"(a0), "+v"(b0));
          asm("v_permlane32_swap_b32 %0, %1" : "+v"(a1), "+v"(b1));
          frag[kb * 2 + cc][0] = a0;
          frag[kb * 2 + cc][1] = a1;
          frag[kb * 2 + cc][2] = b0;
          frag[kb * 2 + cc][3] = b1;
        }
      }

      // ---- O^T += V^T P^T ; L += 1^T P^T (ones-MFMA row-sum) ----
      __builtin_amdgcn_s_setprio(1);
#pragma unroll
      for (int c2 = 0; c2 < 4; c2++) {
        union { u32 u[4]; bf16x8 v; } pb;
        pb.u[0] = frag[c2][0]; pb.u[1] = frag[c2][1];
        pb.u[2] = frag[c2][2]; pb.u[3] = frag[c2][3];
        bf16x8 aV0 = *(const bf16x8*)&Vc[((c2 * 2 + hi) * 64 + lq) * 8];
        bf16x8 aV1 = *(const bf16x8*)&Vc[((c2 * 2 + hi) * 64 + 32 + lq) * 8];
        accL = __builtin_amdgcn_mfma_f32_32x32x16_bf16(aOnes, pb.v, accL, 0, 0, 0);
        accO0 = __builtin_amdgcn_mfma_f32_32x32x16_bf16(aV0, pb.v, accO0, 0, 0, 0);
        accO1 = __builtin_amdgcn_mfma_f32_32x32x16_bf16(aV1, pb.v, accO1, 0, 0, 0);
      }
      __builtin_amdgcn_s_setprio(0);
    }
    __builtin_amdgcn_s_barrier();
    __builtin_amdgcn_sched_barrier(0);
  }

  // accL: every reg = sum over all 2048 keys for col q=lq -> no cross-lane reduce
  float inv = 1.f / accL[0];
  long tq = tok0 + q0 + wv * 32 + lq;
  u16* op = &out[tq * 1024 + h * 64 + hi * 4];
#pragma unroll
  for (int qd = 0; qd < 4; qd++) {
    u16x4 o4, o5;
#pragma unroll
    for (int j = 0; j < 4; j++) {
      o4[j] = f2bf(accO0[qd * 4 + j] * inv);
      o5[j] = f2bf(accO1[qd * 4 + j] * inv);
    }
    *(u16x4*)(op + qd * 8) = o4;
    *(u16x4*)(op + 32 + qd * 8) = o5;
  }
}

// ---------------- fused add + layernorm: v = x + p0 + p1 + bias ----------------
// XBF: x input is bf16. OF32: write f32 out; else write bf16 out.
template <int XBF, int OF32>
__global__ __launch_bounds__(256) void ln_kernel(const void* __restrict__ xin,
                                                 const u16* __restrict__ p0,
                                                 const u16* __restrict__ p1,
                                                 const float* __restrict__ bias,
                                                 const float* __restrict__ g,
                                                 const float* __restrict__ be,
                                                 float* __restrict__ of,
                                                 u16* __restrict__ ob) {
  int row = blockIdx.x, t = threadIdx.x;
  long base = (long)row * 1024 + t * 4;
  f32x4 a;
  if (XBF) {
    u16x4 xa = *((const u16x4*)xin + row * 256 + t);
#pragma unroll
    for (int j = 0; j < 4; j++) a[j] = bf2f(xa[j]);
  } else {
    a = *((const f32x4*)xin + row * 256 + t);
  }
  u16x4 u0 = *(const u16x4*)(p0 + base);
  u16x4 u1 = *(const u16x4*)(p1 + base);
  f32x4 bb4 = *(const f32x4*)(bias + t * 4);
  f32x4 v;
#pragma unroll
  for (int j = 0; j < 4; j++) v[j] = a[j] + bf2f(u0[j]) + bf2f(u1[j]) + bb4[j];
  float s = v[0] + v[1] + v[2] + v[3];
  float ss = v[0] * v[0] + v[1] * v[1] + v[2] * v[2] + v[3] * v[3];
#pragma unroll
  for (int o = 1; o < 64; o <<= 1) { s += __shfl_xor(s, o); ss += __shfl_xor(ss, o); }
  __shared__ float sm[8];
  if ((t & 63) == 0) { sm[t >> 6] = s; sm[4 + (t >> 6)] = ss; }
  __syncthreads();
  s = sm[0] + sm[1] + sm[2] + sm[3];
  ss = sm[4] + sm[5] + sm[6] + sm[7];
  float mu = s * 0.0009765625f;
  float var = ss * 0.0009765625f - mu * mu;
  float inv = rsqrtf(var + 1e-5f);
  f32x4 gg = *(const f32x4*)(g + t * 4);
  f32x4 bb = *(const f32x4*)(be + t * 4);
  f32x4 y;
#pragma unroll
  for (int j = 0; j < 4; j++) y[j] = (v[j] - mu) * inv * gg[j] + bb[j];
  if (OF32) {
    *(f32x4*)(of + base) = y;
  } else {
    u16x4 o4;
#pragma unroll
    for (int j = 0; j < 4; j++) o4[j] = f2bf(y[j]);
    *(u16x4*)(ob + base) = o4;
  }
}

// ---------------- launch ----------------
extern "C" void kernel_launch(void* const* d_in, const int* in_sizes, int n_in,
                              void* d_out, int out_size, void* d_ws, size_t ws_size,
                              hipStream_t stream) {
  const float* x = (const float*)d_in[0];
  const float* Wqkv = (const float*)d_in[1];
  const float* Wo = (const float*)d_in[2];
  const float* bo = (const float*)d_in[3];
  const float* g1 = (const float*)d_in[4];
  const float* be1 = (const float*)d_in[5];
  const float* W1 = (const float*)d_in[6];
  const float* b1 = (const float*)d_in[7];
  const float* W2 = (const float*)d_in[8];
  const float* b2 = (const float*)d_in[9];
  const float* g2 = (const float*)d_in[10];
  const float* be2 = (const float*)d_in[11];
  float* out = (float*)d_out;
  char* ws = (char*)d_ws;

  // workspace layout (bytes), lifetime-overlaid (~159.4MB):
  u16* xb = (u16*)(ws + 0);                 // 16.78M [prep -> qkv]
  u16* qb = (u16*)(ws + 16777216);          // 16.78M [qkv -> attn]
  u16* kt2b = (u16*)(ws + 33554432);        // 16.78M [qkv -> attn]
  u16* vt2b = (u16*)(ws + 50331648);        // 16.78M [qkv -> attn]
  u16* h1b = (u16*)(ws + 0);                // 67.11M [mlp1 -> mlp2] reuses xb+qb+kt2+vt2
  u16* attnb = (u16*)(ws + 67108864);       // 16.78M [attn -> proj]
  u16* x1b = (u16*)(ws + 83886080);         // 16.78M [ln1 -> ln2]
  u16* pp = (u16*)(ws + 100663296);         // 33.55M [proj partials -> ln1]
  u16* ffp = (u16*)(ws + 100663296);        // 33.55M [mlp2 partials -> ln2] reuses pp
  u16* wqkvt = (u16*)(ws + 134217728);      // 6.29M
  u16* wot = (u16*)(ws + 140509184);        // 2.10M
  u16* w1t = (u16*)(ws + 142606336);        // 8.39M
  u16* w2t = (u16*)(ws + 150994944);        // 8.39M (end 159.4M)

  // fused prep: x cvt + all 4 weight transposes (1 launch instead of 5)
  prep_kernel<<<20480, 256, 0, stream>>>(x, xb, Wqkv, wqkvt, Wo, wot, W1, w1t, W2, w2t);
  // qkv = x @ Wqkv: Q prescaled -> qb; K -> kt2 chunked; V -> vt2 chunked
  gemm8p<0, 0, 0, 1, 0><<<dim3(12, 32, 1), 512, 0, stream>>>(
      xb, wqkvt, qb, nullptr, kt2b, vt2b, 8192, 3072, 1024, 1024);
  attn_kernel<<<512, 512, 0, stream>>>(qb, kt2b, vt2b, attnb);
  // proj partials = attn @ Wo (split-K x2, bf16 partials; bias+reduce in LN1)
  gemm8p<0, 0, 0, 0, 1><<<dim3(4, 32, 2), 512, 0, stream>>>(
      attnb, wot, pp, nullptr, nullptr, nullptr, 8192, 1024, 1024, 512);
  // x1 = LN(x + pp0 + pp1 + bo) -> bf16 only
  ln_kernel<0, 0><<<8192, 256, 0, stream>>>(x, pp, pp + (long)8192 * 1024, bo,
                                            g1, be1, nullptr, x1b);
  // h1 = gelu(x1 @ W1 + b1)
  gemm8p<1, 1, 1, 0, 0><<<dim3(16, 32, 1), 512, 0, stream>>>(
      x1b, w1t, h1b, b1, nullptr, nullptr, 8192, 4096, 1024, 1024);
  // ff partials = h1 @ W2 (split-K x2, bf16 partials; bias+reduce in LN2)
  gemm8p<0, 0, 0, 0, 1><<<dim3(4, 32, 2), 512, 0, stream>>>(
      h1b, w2t, ffp, nullptr, nullptr, nullptr, 8192, 1024, 4096, 2048);
  // out = LN(x1 + ffp0 + ffp1 + b2) -> f32
  ln_kernel<1, 1><<<8192, 256, 0, stream>>>(x1b, ffp, ffp + (long)8192 * 1024, b2,
                                            g2, be2, out, nullptr);
}

// Round 14
// 380.560 us; speedup vs baseline: 1.0483x; 1.0112x over previous
//
#include <hip/hip_runtime.h>

typedef unsigned short u16;
typedef unsigned int u32;
typedef __attribute__((ext_vector_type(4))) float f32x4;
typedef __attribute__((ext_vector_type(16))) float f32x16;
typedef __attribute__((ext_vector_type(8))) __bf16 bf16x8;
typedef __attribute__((ext_vector_type(8))) unsigned short u16x8;
typedef __attribute__((ext_vector_type(4))) unsigned short u16x4;

__device__ __forceinline__ u16 f2bf(float f) {
  __bf16 h = (__bf16)f;
  union { __bf16 h; u16 u; } v; v.h = h;
  return v.u;
}

__device__ __forceinline__ float bf2f(u16 u) {
  union { unsigned u; float f; } v; v.u = ((unsigned)u) << 16;
  return v.f;
}

__device__ __forceinline__ u32 pk2(float a, float b) {
  return (u32)f2bf(a) | ((u32)f2bf(b) << 16);
}

__device__ __forceinline__ void async16(const void* g, void* l) {
  __builtin_amdgcn_global_load_lds(
      (const __attribute__((address_space(1))) unsigned int*)g,
      (__attribute__((address_space(3))) unsigned int*)l, 16, 0, 0);
}

__device__ __forceinline__ void barrier_f() {
  asm volatile("" ::: "memory");
  __builtin_amdgcn_s_barrier();
  asm volatile("" ::: "memory");
}

// ---------------- fused prep: x cvt + 4 weight transposes (one launch) ----------------
__device__ __forceinline__ void tcvt_body(const float* __restrict__ W, u16* __restrict__ Wt,
                                          int K, int N, int bx, int by, int t,
                                          float (*tile)[33]) {
  int n0 = bx * 32, k0 = by * 32;
  int tx = t & 31, ty = t >> 5;
#pragma unroll
  for (int i = 0; i < 32; i += 8)
    tile[ty + i][tx] = W[(long)(k0 + ty + i) * N + n0 + tx];
  __syncthreads();
#pragma unroll
  for (int i = 0; i < 32; i += 8)
    Wt[(long)(n0 + ty + i) * K + k0 + tx] = f2bf(tile[tx][ty + i]);
}

__global__ __launch_bounds__(256) void prep_kernel(const float* __restrict__ x,
                                                   u16* __restrict__ xb,
                                                   const float* __restrict__ Wqkv,
                                                   u16* __restrict__ wqkvt,
                                                   const float* __restrict__ Wo,
                                                   u16* __restrict__ wot,
                                                   const float* __restrict__ W1,
                                                   u16* __restrict__ w1t,
                                                   const float* __restrict__ W2,
                                                   u16* __restrict__ w2t) {
  __shared__ float tile[32][33];
  const int b = blockIdx.x, t = threadIdx.x;
  if (b < 8192) {
    long i = (long)b * 256 + t;
    f32x4 v = *(const f32x4*)(x + i * 4);
    u16x4 o;
#pragma unroll
    for (int j = 0; j < 4; j++) o[j] = f2bf(v[j]);
    *(u16x4*)(xb + i * 4) = o;
  } else if (b < 8192 + 3072) {
    int b2 = b - 8192;
    tcvt_body(Wqkv, wqkvt, 1024, 3072, b2 % 96, b2 / 96, t, tile);
  } else if (b < 8192 + 3072 + 1024) {
    int b2 = b - (8192 + 3072);
    tcvt_body(Wo, wot, 1024, 1024, b2 % 32, b2 / 32, t, tile);
  } else if (b < 8192 + 3072 + 1024 + 4096) {
    int b2 = b - (8192 + 3072 + 1024);
    tcvt_body(W1, w1t, 1024, 4096, b2 % 128, b2 / 128, t, tile);
  } else {
    int b2 = b - (8192 + 3072 + 1024 + 4096);
    tcvt_body(W2, w2t, 4096, 1024, b2 % 32, b2 / 32, t, tile);
  }
}

// ======== 8-phase GEMM 256x256, BK=64, 8 waves (2M x 4N), counted vmcnt ========
// QKV: col<1024 -> qb prescaled (direct); K/V sections routed through LDS for
//      coalesced u16x8 granule stores into kt2/vt2 chunk-major layouts.
// SPLITK: raw bf16 partials to Cp + z*M*N (reduce fused into LN).
template <int BIAS, int GELU, int OBF, int QKV, int SPLITK>
__global__ __launch_bounds__(512, 1) void gemm8p(const u16* __restrict__ A,
                                                 const u16* __restrict__ Bt,
                                                 void* __restrict__ Cp,
                                                 const float* __restrict__ bias,
                                                 u16* __restrict__ kt2,
                                                 u16* __restrict__ vt2,
                                                 int M, int N, int Kst, int Klen) {
  __shared__ u16 SH[65536];   // 128KB: [A dbuf 64KB][B dbuf 64KB]; reused by QKV epilogue
  const int t = threadIdx.x, wid = t >> 6, ln = t & 63;
  const int lr = ln & 15, lg = ln >> 4;
  const int wr = wid >> 2, wc = wid & 3;

  const int gx = gridDim.x, gy = gridDim.y;
  const int nwg = gx * gy * gridDim.z;
  const int flat = (blockIdx.z * gy + blockIdx.y) * gx + blockIdx.x;
  const int cpx = nwg >> 3;
  const int swz = (flat & 7) * cpx + (flat >> 3);
  const int sx = swz % gx, rest = swz / gx;
  const int sy = rest % gy, sz = rest / gy;
  const int m0 = sy * 256, n0 = sx * 256;
  const long zo = (long)sz * Klen;
  const int NT = Klen >> 6;

  const int srow = t >> 3;
  const int sch = ((t & 7) ^ (srow & 7)) * 8;
  const u16* gA = A + (long)(m0 + srow) * Kst + zo + sch;
  const u16* gB = Bt + (long)(n0 + srow) * Kst + zo + sch;
  const long KL = Kst;

#define STAGE_A(tt, h)                                                     \
  {                                                                        \
    const u16* s_ = gA + (long)((h) * 128) * KL + (long)(tt) * 64;         \
    char* d_ = (char*)SH + ((tt) & 1) * 32768 + (h) * 16384 + wid * 1024;  \
    async16(s_, d_);                                                       \
    async16(s_ + 64 * KL, d_ + 8192);                                      \
  }
#define STAGE_B(tt, h)                                                     \
  {                                                                        \
    const u16* s_ = gB + (long)((h) * 128) * KL + (long)(tt) * 64;         \
    char* d_ = (char*)SH + 65536 + ((tt) & 1) * 32768 + (h) * 16384 + wid * 1024; \
    async16(s_, d_);                                                       \
    async16(s_ + 64 * KL, d_ + 8192);                                      \
  }

  f32x4 acc[8][4] = {};
  const int cx0 = (lg ^ (lr & 7)) * 16;
  const int cx1 = ((4 + lg) ^ (lr & 7)) * 16;

  STAGE_A(0, 0); STAGE_A(0, 1);
  STAGE_B(0, 0); STAGE_B(0, 1);
  STAGE_A(1, 0); STAGE_A(1, 1);

  for (int tK = 0; tK < NT; ++tK) {
    const int cur = tK & 1;
    const char* ldsA = (const char*)SH + cur * 32768;
    const char* ldsB = (const char*)SH + 65536 + cur * 32768;
    if (tK == NT - 1) {
      asm volatile("s_waitcnt vmcnt(0)" ::: "memory");
    } else {
      asm volatile("s_waitcnt vmcnt(4)" ::: "memory");
    }
    barrier_f();

    bf16x8 aLo[4][2], aHi[4][2], bLo[2][2], bHi[2][2];
#pragma unroll
    for (int mf = 0; mf < 4; mf++) {
      int row = wr * 128 + mf * 16 + lr;
      aLo[mf][0] = *(const bf16x8*)(ldsA + row * 128 + cx0);
      aLo[mf][1] = *(const bf16x8*)(ldsA + row * 128 + cx1);
    }
#pragma unroll
    for (int nf = 0; nf < 2; nf++) {
      int row = wc * 64 + nf * 16 + lr;
      bLo[nf][0] = *(const bf16x8*)(ldsB + row * 128 + cx0);
      bLo[nf][1] = *(const bf16x8*)(ldsB + row * 128 + cx1);
    }
    if (tK + 1 < NT) STAGE_B(tK + 1, 0);
    barrier_f();
    __builtin_amdgcn_s_setprio(1);
#pragma unroll
    for (int mf = 0; mf < 4; mf++)
#pragma unroll
      for (int nf = 0; nf < 2; nf++) {
        acc[mf][nf] = __builtin_amdgcn_mfma_f32_16x16x32_bf16(aLo[mf][0], bLo[nf][0], acc[mf][nf], 0, 0, 0);
        acc[mf][nf] = __builtin_amdgcn_mfma_f32_16x16x32_bf16(aLo[mf][1], bLo[nf][1], acc[mf][nf], 0, 0, 0);
      }
    __builtin_amdgcn_s_setprio(0);
    barrier_f();

#pragma unroll
    for (int mf = 0; mf < 4; mf++) {
      int row = wr * 128 + (mf + 4) * 16 + lr;
      aHi[mf][0] = *(const bf16x8*)(ldsA + row * 128 + cx0);
      aHi[mf][1] = *(const bf16x8*)(ldsA + row * 128 + cx1);
    }
    if (tK + 1 < NT) STAGE_B(tK + 1, 1);
    barrier_f();
    __builtin_amdgcn_s_setprio(1);
#pragma unroll
    for (int mf = 0; mf < 4; mf++)
#pragma unroll
      for (int nf = 0; nf < 2; nf++) {
        acc[mf + 4][nf] = __builtin_amdgcn_mfma_f32_16x16x32_bf16(aHi[mf][0], bLo[nf][0], acc[mf + 4][nf], 0, 0, 0);
        acc[mf + 4][nf] = __builtin_amdgcn_mfma_f32_16x16x32_bf16(aHi[mf][1], bLo[nf][1], acc[mf + 4][nf], 0, 0, 0);
      }
    __builtin_amdgcn_s_setprio(0);
    barrier_f();

#pragma unroll
    for (int nf = 0; nf < 2; nf++) {
      int row = wc * 64 + (nf + 2) * 16 + lr;
      bHi[nf][0] = *(const bf16x8*)(ldsB + row * 128 + cx0);
      bHi[nf][1] = *(const bf16x8*)(ldsB + row * 128 + cx1);
    }
    if (tK + 2 < NT) STAGE_A(tK + 2, 0);
    barrier_f();
    __builtin_amdgcn_s_setprio(1);
#pragma unroll
    for (int mf = 0; mf < 4; mf++)
#pragma unroll
      for (int nf = 0; nf < 2; nf++) {
        acc[mf][nf + 2] = __builtin_amdgcn_mfma_f32_16x16x32_bf16(aLo[mf][0], bHi[nf][0], acc[mf][nf + 2], 0, 0, 0);
        acc[mf][nf + 2] = __builtin_amdgcn_mfma_f32_16x16x32_bf16(aLo[mf][1], bHi[nf][1], acc[mf][nf + 2], 0, 0, 0);
      }
    __builtin_amdgcn_s_setprio(0);
    barrier_f();

    if (tK + 2 < NT) STAGE_A(tK + 2, 1);
    barrier_f();
    __builtin_amdgcn_s_setprio(1);
#pragma unroll
    for (int mf = 0; mf < 4; mf++)
#pragma unroll
      for (int nf = 0; nf < 2; nf++) {
        acc[mf + 4][nf + 2] = __builtin_amdgcn_mfma_f32_16x16x32_bf16(aHi[mf][0], bHi[nf][0], acc[mf + 4][nf + 2], 0, 0, 0);
        acc[mf + 4][nf + 2] = __builtin_amdgcn_mfma_f32_16x16x32_bf16(aHi[mf][1], bHi[nf][1], acc[mf + 4][nf + 2], 0, 0, 0);
      }
    __builtin_amdgcn_s_setprio(0);
    barrier_f();
  }
#undef STAGE_A
#undef STAGE_B

  if (QKV && n0 >= 1024) {
    // ---- K/V sections: stage C-tile in LDS (swizzled), emit coalesced u16x8 ----
    const int isV = (n0 >= 2048);
    const int bq = m0 >> 11;
    barrier_f();   // all LDS reads of the K-loop are done (trailing barrier passed), safe
    if (!isV) {
      // K: row-major SH[key(256)][swz-chunk(32)x8]; swz: chunk ^= (key & 31)
#pragma unroll
      for (int mf = 0; mf < 8; mf++) {
        int rr = wr * 128 + mf * 16 + lg * 4;
#pragma unroll
        for (int nf = 0; nf < 4; nf++) {
          int cc = wc * 64 + nf * 16 + lr;
          int base = ((cc >> 3) ^ 0) * 8 + (cc & 7);   // chunk part; row-XOR applied per r
#pragma unroll
          for (int r = 0; r < 4; r++) {
            int row = rr + r;
            SH[row * 256 + ((((cc >> 3) ^ (row & 31)) * 8) | (cc & 7))] = f2bf(acc[mf][nf][r]);
          }
          (void)base;
        }
      }
      barrier_f();
      const int h0 = (n0 - 1024) >> 6;
      const int kt0 = (m0 & 2047) >> 6;
#pragma unroll
      for (int i = 0; i < 16; i++) {
        int gid = i * 512 + t;
        int key = gid & 255, dchunk = gid >> 8;
        u16x8 v = *(const u16x8*)&SH[key * 256 + ((dchunk ^ (key & 31)) * 8)];
        long addr = ((((long)(bq * 16 + h0 + (dchunk >> 3)) * 32 + kt0 + (key >> 6)) * 8 +
                      (dchunk & 7)) * 64 + (key & 63)) * 8;
        *(u16x8*)&kt2[addr] = v;
      }
    } else {
      // V: col-major SH[d(256)][swz-keychunk(32)x8]; swz: kc ^= (d & 31)
#pragma unroll
      for (int mf = 0; mf < 8; mf++) {
        int rr = wr * 128 + mf * 16 + lg * 4;
        int rc = rr >> 3, rlo = rr & 7;
#pragma unroll
        for (int nf = 0; nf < 4; nf++) {
          int cc = wc * 64 + nf * 16 + lr;
          u16x4 o4;
#pragma unroll
          for (int r = 0; r < 4; r++) o4[r] = f2bf(acc[mf][nf][r]);
          *(u16x4*)&SH[cc * 256 + (((rc ^ (cc & 31)) * 8) | rlo)] = o4;
        }
      }
      barrier_f();
      const int h0 = (n0 - 2048) >> 6;
      const int kt0 = (m0 & 2047) >> 6;
#pragma unroll
      for (int i = 0; i < 16; i++) {
        int gid = i * 512 + t;
        int d = gid & 255, kc = gid >> 8;
        u16x8 v = *(const u16x8*)&SH[d * 256 + ((kc ^ (d & 31)) * 8)];
        long addr = ((((long)(bq * 16 + h0 + (d >> 6)) * 32 + kt0 + (kc >> 3)) * 8 +
                      (kc & 7)) * 64 + (d & 63)) * 8;
        *(u16x8*)&vt2[addr] = v;
      }
    }
    return;
  }

  u16* const Cu = (u16*)Cp + (SPLITK ? (long)sz * M * N : 0);
#pragma unroll
  for (int mf = 0; mf < 8; mf++) {
    int rbase = m0 + wr * 128 + mf * 16 + lg * 4;
#pragma unroll
    for (int nf = 0; nf < 4; nf++) {
      int col = n0 + wc * 64 + nf * 16 + lr;
      float bv = BIAS ? bias[col] : 0.f;
      if (QKV) {
        // Q: prescaled for exp2-domain softmax (col < 1024 here)
#pragma unroll
        for (int r = 0; r < 4; r++)
          ((u16*)Cp)[(long)(rbase + r) * 1024 + col] = f2bf(acc[mf][nf][r] * 0.18033688011112043f);
      } else if (SPLITK) {
#pragma unroll
        for (int r = 0; r < 4; r++)
          Cu[(long)(rbase + r) * N + col] = f2bf(acc[mf][nf][r]);
      } else {
#pragma unroll
        for (int r = 0; r < 4; r++) {
          float v = acc[mf][nf][r] + bv;
          if (GELU) v = v / (1.f + __expf(-1.702f * v));
          if (OBF) ((u16*)Cp)[(long)(rbase + r) * N + col] = f2bf(v);
          else ((float*)Cp)[(long)(rbase + r) * N + col] = v;
        }
      }
    }
  }
}

// ---------------- flash attention v6: 32x32 MFMA, KVBLK=128, XCD-local K/V ----------------
__global__ __launch_bounds__(512, 4) void attn_kernel(const u16* __restrict__ qb,
                                                      const u16* __restrict__ kt2,
                                                      const u16* __restrict__ vt2,
                                                      u16* __restrict__ out) {
  const int flat = blockIdx.x;
  const int bh_low = flat & 7, rest = flat >> 3;
  const int qi = rest & 7;
  const int bh = ((rest >> 3) << 3) | bh_low;
  const int h = bh & 15;
  const int q0 = qi * 256;
  const int t = threadIdx.x, wv = t >> 6, ln = t & 63;
  const int lq = ln & 31, hi = ln >> 5;
  __shared__ u16 Ks[2][8192];
  __shared__ u16 Vs[2][8192];
  const long tok0 = (long)(bh >> 4) * 2048;

  bf16x8 bQ[4];
  {
    long row = tok0 + q0 + wv * 32 + lq;
    const u16* qp = &qb[row * 1024 + h * 64 + hi * 8];
#pragma unroll
    for (int c = 0; c < 4; c++) bQ[c] = *(const bf16x8*)(qp + c * 16);
  }

  const int isK = (t < 256);
  const int tt = t & 255;
  const u16* gS = (isK ? kt2 : vt2) + (long)bh * 131072 + tt * 8;
  char* const dS = (isK ? (char*)&Ks[0][0] : (char*)&Vs[0][0]) + (wv & 3) * 1024;

  f32x16 accO0 = {}, accO1 = {}, accL = {};

  bf16x8 aOnes;
  {
    union { u16x8 u; bf16x8 b; } ou;
#pragma unroll
    for (int j = 0; j < 8; j++) ou.u[j] = 0x3F80;
    aOnes = ou.b;
  }

#pragma unroll
  for (int i = 0; i < 4; i++) async16(gS + i * 2048, dS + i * 4096);
  gS += 8192;

  for (int it = 0; it < 16; ++it) {
    const int cur = it & 1;
    if (it < 15) {
      char* nS = dS + (cur ^ 1) * 16384;
#pragma unroll
      for (int i = 0; i < 4; i++) async16(gS + i * 2048, nS + i * 4096);
      gS += 8192;
      asm volatile("s_waitcnt vmcnt(4)" ::: "memory");
    } else {
      asm volatile("s_waitcnt vmcnt(0)" ::: "memory");
    }
    __builtin_amdgcn_s_barrier();
    __builtin_amdgcn_sched_barrier(0);

#pragma unroll
    for (int sub = 0; sub < 2; ++sub) {
      const u16* Kc = &Ks[cur][sub * 4096];
      const u16* Vc = &Vs[cur][sub * 4096];

      u32 frag[4][4];
#pragma unroll
      for (int kb = 0; kb < 2; kb++) {
        f32x16 s = {};
        __builtin_amdgcn_s_setprio(1);
#pragma unroll
        for (int c = 0; c < 4; c++) {
          bf16x8 aK = *(const bf16x8*)&Kc[((c * 2 + hi) * 64 + kb * 32 + lq) * 8];
          s = __builtin_amdgcn_mfma_f32_32x32x16_bf16(aK, bQ[c], s, 0, 0, 0);
        }
        __builtin_amdgcn_s_setprio(0);
        float pv[16];
#pragma unroll
        for (int r = 0; r < 16; r++) pv[r] = exp2f(s[r]);
#pragma unroll
        for (int cc = 0; cc < 2; cc++) {
          u32 a0 = pk2(pv[8 * cc + 0], pv[8 * cc + 1]);
          u32 a1 = pk2(pv[8 * cc + 2], pv[8 * cc + 3]);
          u32 b0 = pk2(pv[8 * cc + 4], pv[8 * cc + 5]);
          u32 b1 = pk2(pv[8 * cc + 6], pv[8 * cc + 7]);
          asm("v_permlane32_swap_b32 %0, %1" : "+v"(a0), "+v"(b0));
          asm("v_permlane32_swap_b32 %0, %1" : "+v"(a1), "+v"(b1));
          frag[kb * 2 + cc][0] = a0;
          frag[kb * 2 + cc][1] = a1;
          frag[kb * 2 + cc][2] = b0;
          frag[kb * 2 + cc][3] = b1;
        }
      }

      __builtin_amdgcn_s_setprio(1);
#pragma unroll
      for (int c2 = 0; c2 < 4; c2++) {
        union { u32 u[4]; bf16x8 v; } pb;
        pb.u[0] = frag[c2][0]; pb.u[1] = frag[c2][1];
        pb.u[2] = frag[c2][2]; pb.u[3] = frag[c2][3];
        bf16x8 aV0 = *(const bf16x8*)&Vc[((c2 * 2 + hi) * 64 + lq) * 8];
        bf16x8 aV1 = *(const bf16x8*)&Vc[((c2 * 2 + hi) * 64 + 32 + lq) * 8];
        accL = __builtin_amdgcn_mfma_f32_32x32x16_bf16(aOnes, pb.v, accL, 0, 0, 0);
        accO0 = __builtin_amdgcn_mfma_f32_32x32x16_bf16(aV0, pb.v, accO0, 0, 0, 0);
        accO1 = __builtin_amdgcn_mfma_f32_32x32x16_bf16(aV1, pb.v, accO1, 0, 0, 0);
      }
      __builtin_amdgcn_s_setprio(0);
    }
    __builtin_amdgcn_s_barrier();
    __builtin_amdgcn_sched_barrier(0);
  }

  float inv = 1.f / accL[0];
  long tq = tok0 + q0 + wv * 32 + lq;
  u16* op = &out[tq * 1024 + h * 64 + hi * 4];
#pragma unroll
  for (int qd = 0; qd < 4; qd++) {
    u16x4 o4, o5;
#pragma unroll
    for (int j = 0; j < 4; j++) {
      o4[j] = f2bf(accO0[qd * 4 + j] * inv);
      o5[j] = f2bf(accO1[qd * 4 + j] * inv);
    }
    *(u16x4*)(op + qd * 8) = o4;
    *(u16x4*)(op + 32 + qd * 8) = o5;
  }
}

// ---------------- fused add + layernorm: v = x + p0 + p1 + bias ----------------
template <int XBF, int OF32>
__global__ __launch_bounds__(256) void ln_kernel(const void* __restrict__ xin,
                                                 const u16* __restrict__ p0,
                                                 const u16* __restrict__ p1,
                                                 const float* __restrict__ bias,
                                                 const float* __restrict__ g,
                                                 const float* __restrict__ be,
                                                 float* __restrict__ of,
                                                 u16* __restrict__ ob) {
  int row = blockIdx.x, t = threadIdx.x;
  long base = (long)row * 1024 + t * 4;
  f32x4 a;
  if (XBF) {
    u16x4 xa = *((const u16x4*)xin + row * 256 + t);
#pragma unroll
    for (int j = 0; j < 4; j++) a[j] = bf2f(xa[j]);
  } else {
    a = *((const f32x4*)xin + row * 256 + t);
  }
  u16x4 u0 = *(const u16x4*)(p0 + base);
  u16x4 u1 = *(const u16x4*)(p1 + base);
  f32x4 bb4 = *(const f32x4*)(bias + t * 4);
  f32x4 v;
#pragma unroll
  for (int j = 0; j < 4; j++) v[j] = a[j] + bf2f(u0[j]) + bf2f(u1[j]) + bb4[j];
  float s = v[0] + v[1] + v[2] + v[3];
  float ss = v[0] * v[0] + v[1] * v[1] + v[2] * v[2] + v[3] * v[3];
#pragma unroll
  for (int o = 1; o < 64; o <<= 1) { s += __shfl_xor(s, o); ss += __shfl_xor(ss, o); }
  __shared__ float sm[8];
  if ((t & 63) == 0) { sm[t >> 6] = s; sm[4 + (t >> 6)] = ss; }
  __syncthreads();
  s = sm[0] + sm[1] + sm[2] + sm[3];
  ss = sm[4] + sm[5] + sm[6] + sm[7];
  float mu = s * 0.0009765625f;
  float var = ss * 0.0009765625f - mu * mu;
  float inv = rsqrtf(var + 1e-5f);
  f32x4 gg = *(const f32x4*)(g + t * 4);
  f32x4 bb = *(const f32x4*)(be + t * 4);
  f32x4 y;
#pragma unroll
  for (int j = 0; j < 4; j++) y[j] = (v[j] - mu) * inv * gg[j] + bb[j];
  if (OF32) {
    *(f32x4*)(of + base) = y;
  } else {
    u16x4 o4;
#pragma unroll
    for (int j = 0; j < 4; j++) o4[j] = f2bf(y[j]);
    *(u16x4*)(ob + base) = o4;
  }
}

// ---------------- launch ----------------
extern "C" void kernel_launch(void* const* d_in, const int* in_sizes, int n_in,
                              void* d_out, int out_size, void* d_ws, size_t ws_size,
                              hipStream_t stream) {
  const float* x = (const float*)d_in[0];
  const float* Wqkv = (const float*)d_in[1];
  const float* Wo = (const float*)d_in[2];
  const float* bo = (const float*)d_in[3];
  const float* g1 = (const float*)d_in[4];
  const float* be1 = (const float*)d_in[5];
  const float* W1 = (const float*)d_in[6];
  const float* b1 = (const float*)d_in[7];
  const float* W2 = (const float*)d_in[8];
  const float* b2 = (const float*)d_in[9];
  const float* g2 = (const float*)d_in[10];
  const float* be2 = (const float*)d_in[11];
  float* out = (float*)d_out;
  char* ws = (char*)d_ws;

  u16* xb = (u16*)(ws + 0);
  u16* qb = (u16*)(ws + 16777216);
  u16* kt2b = (u16*)(ws + 33554432);
  u16* vt2b = (u16*)(ws + 50331648);
  u16* h1b = (u16*)(ws + 0);
  u16* attnb = (u16*)(ws + 67108864);
  u16* x1b = (u16*)(ws + 83886080);
  u16* pp = (u16*)(ws + 100663296);
  u16* ffp = (u16*)(ws + 100663296);
  u16* wqkvt = (u16*)(ws + 134217728);
  u16* wot = (u16*)(ws + 140509184);
  u16* w1t = (u16*)(ws + 142606336);
  u16* w2t = (u16*)(ws + 150994944);

  prep_kernel<<<20480, 256, 0, stream>>>(x, xb, Wqkv, wqkvt, Wo, wot, W1, w1t, W2, w2t);
  gemm8p<0, 0, 0, 1, 0><<<dim3(12, 32, 1), 512, 0, stream>>>(
      xb, wqkvt, qb, nullptr, kt2b, vt2b, 8192, 3072, 1024, 1024);
  attn_kernel<<<512, 512, 0, stream>>>(qb, kt2b, vt2b, attnb);
  gemm8p<0, 0, 0, 0, 1><<<dim3(4, 32, 2), 512, 0, stream>>>(
      attnb, wot, pp, nullptr, nullptr, nullptr, 8192, 1024, 1024, 512);
  ln_kernel<0, 0><<<8192, 256, 0, stream>>>(x, pp, pp + (long)8192 * 1024, bo,
                                            g1, be1, nullptr, x1b);
  gemm8p<1, 1, 1, 0, 0><<<dim3(16, 32, 1), 512, 0, stream>>>(
      x1b, w1t, h1b, b1, nullptr, nullptr, 8192, 4096, 1024, 1024);
  gemm8p<0, 0, 0, 0, 1><<<dim3(4, 32, 2), 512, 0, stream>>>(
      h1b, w2t, ffp, nullptr, nullptr, nullptr, 8192, 1024, 4096, 2048);
  ln_kernel<1, 1><<<8192, 256, 0, stream>>>(x1b, ffp, ffp + (long)8192 * 1024, b2,
                                            g2, be2, out, nullptr);
}